// Round 1
// baseline (3466.145 us; speedup 1.0000x reference)
//
#include <hip/hip_runtime.h>
#include <stdint.h>

// ---------------- setup kernels ----------------

__global__ void k_prep(const float* __restrict__ pa, const float* __restrict__ g0,
                       const float* __restrict__ b0, const float* __restrict__ W1,
                       const float* __restrict__ b1,
                       float* __restrict__ c_pa, float* __restrict__ w_t,
                       float* __restrict__ c_g, float* __restrict__ c_const,
                       float* __restrict__ scal, float* __restrict__ wzT,
                       float* __restrict__ wzZ) {
  int j = threadIdx.x;  // 256 threads, one per W1 row
  const float* wr = W1 + j * 97;
  float cg = 0.f, cc = 0.f, cp = 0.f;
  for (int k = 0; k < 97; ++k) { float w = wr[k]; cg += w * g0[k]; cc += w * b0[k]; }
  for (int k = 0; k < 32; ++k) cp += wr[k] * g0[k] * pa[k];
  c_g[j] = cg;
  c_const[j] = cc + b1[j];
  c_pa[j] = cp;
  w_t[j] = wr[32] * g0[32];
  for (int z = 0; z < 64; ++z) {
    float v = wr[33 + z] * g0[33 + z];
    wzT[j * 64 + z] = v;     // [k][z]
    wzZ[z * 256 + j] = v;    // [z][k]
  }
  if (j == 0) {
    float s = 0.f, q = 0.f;
    for (int k = 0; k < 32; ++k) { float x = pa[k]; s += x; q += x * x; }
    scal[0] = s; scal[1] = q;
  }
}

__global__ void k_adj(const int* __restrict__ ei, unsigned long long* __restrict__ adj) {
  int t = threadIdx.x;  // 256
  if (t < 64) adj[t] = 1ull << t;   // self loops (overwrites stale state each call)
  __syncthreads();
  int u = ei[t] & 63, v = ei[256 + t] & 63;
  atomicOr(&adj[u], 1ull << v);
  atomicOr(&adj[v], 1ull << u);
}

__global__ void k_tr(const float* __restrict__ W2, const float* __restrict__ W3,
                     const float* __restrict__ W4,
                     float* __restrict__ W2T, float* __restrict__ W3T,
                     float* __restrict__ W4T) {
  int idx = blockIdx.x * 256 + threadIdx.x;
  if (idx < 32768) {                     // W2 [128,256] -> W2T [256,128]
    int k = idx >> 7, j = idx & 127;
    W2T[idx] = W2[j * 256 + k];
  } else if (idx < 40960) {              // W3 [64,128] -> W3T [128,64]
    int r = idx - 32768; int k = r >> 6, j = r & 63;
    W3T[r] = W3[j * 128 + k];
  } else if (idx < 45056) {              // W4 [64,64] -> W4T [64,64]
    int r = idx - 40960; int k = r >> 6, j = r & 63;
    W4T[r] = W4[j * 64 + k];
  }
}

// ---------------- pass 1: transition table next[i][z] for all i,z ----------------

__global__ __launch_bounds__(256, 4) void k_pass1(
    const float* __restrict__ times,
    const float* __restrict__ c_pa, const float* __restrict__ w_t,
    const float* __restrict__ c_g, const float* __restrict__ c_const,
    const float* __restrict__ scal, const float* __restrict__ wzT,
    const float* __restrict__ W2T, const float* __restrict__ W3T,
    const float* __restrict__ W4T,
    const float* __restrict__ b2, const float* __restrict__ b3,
    const float* __restrict__ b4,
    const float* __restrict__ g1, const float* __restrict__ be1,
    const float* __restrict__ g2, const float* __restrict__ be2,
    const float* __restrict__ g3, const float* __restrict__ be3,
    const unsigned long long* __restrict__ adj,
    unsigned char* __restrict__ nxt) {
  __shared__ float buf[128 * 64];                 // 32 KB activation tile [row][z]
  __shared__ float ps1[4 * 64], ps2[4 * 64];      // per-wave LN partial sums
  __shared__ unsigned long long pk[4 * 64];       // argmax partials

  const int tid = threadIdx.x;
  const int lane = tid & 63;                      // lane == zone z
  const int wave = tid >> 6;
  const int wv = __builtin_amdgcn_readfirstlane(wave);
  const int i = blockIdx.x;

  const float t = times[i];
  const float m  = (scal[0] + t + 1.0f) * (1.0f / 97.0f);
  const float e2 = (scal[1] + t * t + 1.0f) * (1.0f / 97.0f);
  const float alpha = 1.0f / sqrtf(e2 - m * m + 1e-5f);
  const float gma = -m * alpha;

  // ---- phase A: LN1 statistics over pre1 (no store) ----
  float s1 = 0.f, s2 = 0.f;
  for (int kk = 0; kk < 64; ++kk) {
    int k = wv * 64 + kk;
    float base = alpha * (c_pa[k] + t * w_t[k]) + gma * c_g[k] + c_const[k];
    float p = base + alpha * wzT[k * 64 + lane];
    s1 += p; s2 += p * p;
  }
  ps1[wave * 64 + lane] = s1;
  ps2[wave * 64 + lane] = s2;
  __syncthreads();
  float mu1, inv1;
  {
    float a = ps1[lane] + ps1[64 + lane] + ps1[128 + lane] + ps1[192 + lane];
    float b = ps2[lane] + ps2[64 + lane] + ps2[128 + lane] + ps2[192 + lane];
    mu1 = a * (1.0f / 256.0f);
    inv1 = 1.0f / sqrtf(b * (1.0f / 256.0f) - mu1 * mu1 + 1e-5f);
  }

  // ---- phase B: h1 in 2 K-chunks of 128 rows, fused with W2 GEMM ----
  float acc[32];
  #pragma unroll
  for (int jj = 0; jj < 32; ++jj) acc[jj] = 0.f;
  const int jb2 = wv * 32;

  for (int kc = 0; kc < 2; ++kc) {
    __syncthreads();  // previous chunk's readers done before overwrite
    for (int kk = 0; kk < 32; ++kk) {
      int kl = wv * 32 + kk;
      int k = kc * 128 + kl;
      float base = alpha * (c_pa[k] + t * w_t[k]) + gma * c_g[k] + c_const[k];
      float p = base + alpha * wzT[k * 64 + lane];
      float h = g1[k] * ((p - mu1) * inv1) + be1[k];
      buf[kl * 64 + lane] = fmaxf(h, 0.f);
    }
    __syncthreads();
    for (int kl = 0; kl < 128; ++kl) {
      float hv = buf[kl * 64 + lane];                       // 2-way bank = free
      const float* wr = W2T + (kc * 128 + kl) * 128 + jb2;  // wave-uniform -> s_load
      #pragma unroll
      for (int jj = 0; jj < 32; ++jj) acc[jj] = fmaf(wr[jj], hv, acc[jj]);
    }
  }
  #pragma unroll
  for (int jj = 0; jj < 32; ++jj) acc[jj] += b2[jb2 + jj];
  s1 = 0.f; s2 = 0.f;
  #pragma unroll
  for (int jj = 0; jj < 32; ++jj) { s1 += acc[jj]; s2 += acc[jj] * acc[jj]; }
  ps1[wave * 64 + lane] = s1;
  ps2[wave * 64 + lane] = s2;
  __syncthreads();
  {
    float a = ps1[lane] + ps1[64 + lane] + ps1[128 + lane] + ps1[192 + lane];
    float b = ps2[lane] + ps2[64 + lane] + ps2[128 + lane] + ps2[192 + lane];
    float mu = a * (1.0f / 128.0f);
    float inv = 1.0f / sqrtf(b * (1.0f / 128.0f) - mu * mu + 1e-5f);
    #pragma unroll
    for (int jj = 0; jj < 32; ++jj) {
      int j = jb2 + jj;
      float h = g2[j] * ((acc[jj] - mu) * inv) + be2[j];
      buf[j * 64 + lane] = fmaxf(h, 0.f);   // h2T aliases buf; safe after barrier
    }
  }
  __syncthreads();

  // ---- phase 3: pre3 = W3 @ h2 (+b3), LN3, relu ----
  float acc3[16];
  #pragma unroll
  for (int jj = 0; jj < 16; ++jj) acc3[jj] = 0.f;
  const int jb3 = wv * 16;
  for (int k = 0; k < 128; ++k) {
    float hv = buf[k * 64 + lane];
    const float* wr = W3T + k * 64 + jb3;
    #pragma unroll
    for (int jj = 0; jj < 16; ++jj) acc3[jj] = fmaf(wr[jj], hv, acc3[jj]);
  }
  #pragma unroll
  for (int jj = 0; jj < 16; ++jj) acc3[jj] += b3[jb3 + jj];
  s1 = 0.f; s2 = 0.f;
  #pragma unroll
  for (int jj = 0; jj < 16; ++jj) { s1 += acc3[jj]; s2 += acc3[jj] * acc3[jj]; }
  ps1[wave * 64 + lane] = s1;
  ps2[wave * 64 + lane] = s2;
  __syncthreads();
  {
    float a = ps1[lane] + ps1[64 + lane] + ps1[128 + lane] + ps1[192 + lane];
    float b = ps2[lane] + ps2[64 + lane] + ps2[128 + lane] + ps2[192 + lane];
    float mu = a * (1.0f / 64.0f);
    float inv = 1.0f / sqrtf(b * (1.0f / 64.0f) - mu * mu + 1e-5f);
    #pragma unroll
    for (int jj = 0; jj < 16; ++jj) {
      int j = jb3 + jj;
      float h = g3[j] * ((acc3[jj] - mu) * inv) + be3[j];
      buf[j * 64 + lane] = fmaxf(h, 0.f);   // h3T
    }
  }
  __syncthreads();

  // ---- phase 4: raw = W4 @ h3 + b4, mask, argmax ----
  float acc4[16];
  #pragma unroll
  for (int oo = 0; oo < 16; ++oo) acc4[oo] = 0.f;
  const int ob = wv * 16;
  for (int k = 0; k < 64; ++k) {
    float hv = buf[k * 64 + lane];
    const float* wr = W4T + k * 64 + ob;
    #pragma unroll
    for (int oo = 0; oo < 16; ++oo) acc4[oo] = fmaf(wr[oo], hv, acc4[oo]);
  }
  unsigned long long amask = adj[lane];
  unsigned long long best = 0ull;
  #pragma unroll
  for (int oo = 0; oo < 16; ++oo) {
    int o = ob + oo;
    float raw = acc4[oo] + b4[o];
    float val = ((amask >> o) & 1ull) ? raw : -__builtin_huge_valf();
    unsigned u = __float_as_uint(val);
    u = (u & 0x80000000u) ? ~u : (u | 0x80000000u);  // order-preserving map
    unsigned long long key = ((unsigned long long)u << 6) | (unsigned long long)(63 - o);
    if (key > best) best = key;                       // ties -> lowest o wins
  }
  pk[wave * 64 + lane] = best;
  __syncthreads();
  if (tid < 64) {
    unsigned long long k0 = pk[tid], k1 = pk[64 + tid];
    unsigned long long k2 = pk[128 + tid], k3 = pk[192 + tid];
    unsigned long long a = k0 > k1 ? k0 : k1;
    unsigned long long b = k2 > k3 ? k2 : k3;
    unsigned long long bb = a > b ? a : b;
    nxt[(size_t)i * 64 + tid] = (unsigned char)(63u - (unsigned)(bb & 63ull));
  }
}

// ---------------- trajectory via parallel map-composition scan ----------------

__global__ void k_scan_a(const unsigned char* __restrict__ nxt,
                         unsigned char* __restrict__ cmap) {
  int c = blockIdx.x, lane = threadIdx.x;  // 64 threads
  int g = lane;                            // identity map
  const unsigned char* p = nxt + (size_t)c * 128 * 64;
  for (int s = 0; s < 128; ++s) {
    int sig = p[s * 64 + lane];            // sigma_s[lane]
    g = __shfl(sig, g, 64);                // g = sigma_s[g]
  }
  cmap[c * 64 + lane] = (unsigned char)g;
}

__global__ void k_scan_b(const unsigned char* __restrict__ cmap,
                         int* __restrict__ startz) {
  int lane = threadIdx.x;
  int cur = 0;
  for (int c = 0; c < 256; ++c) {
    if (lane == 0) startz[c] = cur;
    int row = cmap[c * 64 + lane];
    cur = __shfl(row, cur, 64);            // uniform broadcast of F_c[cur]
  }
}

__global__ void k_scan_c(const unsigned char* __restrict__ nxt,
                         const int* __restrict__ startz,
                         unsigned char* __restrict__ zones) {
  int c = blockIdx.x, lane = threadIdx.x;
  int cur = startz[c];
  const unsigned char* p = nxt + (size_t)c * 128 * 64;
  for (int s = 0; s < 128; ++s) {
    if (lane == 0) zones[c * 128 + s] = (unsigned char)cur;
    int row = p[s * 64 + lane];
    cur = __shfl(row, cur, 64);
  }
}

// ---------------- pass 3: logits for the actual zone at each step ----------------

__global__ void k_pass3(
    const float* __restrict__ times, const unsigned char* __restrict__ zones,
    const float* __restrict__ c_pa, const float* __restrict__ w_t,
    const float* __restrict__ c_g, const float* __restrict__ c_const,
    const float* __restrict__ scal, const float* __restrict__ wzZ,
    const float* __restrict__ W2T, const float* __restrict__ W3T,
    const float* __restrict__ W4T,
    const float* __restrict__ b2, const float* __restrict__ b3,
    const float* __restrict__ b4,
    const float* __restrict__ g1, const float* __restrict__ be1,
    const float* __restrict__ g2, const float* __restrict__ be2,
    const float* __restrict__ g3, const float* __restrict__ be3,
    const unsigned long long* __restrict__ adj,
    float* __restrict__ out) {
  __shared__ float h1s[4][256];
  __shared__ float h2s[4][128];
  __shared__ float h3s[4][64];
  const int tid = threadIdx.x, lane = tid & 63, w = tid >> 6;
  const int i = blockIdx.x * 4 + w;            // one timestep per wave
  const int z = zones[i];
  const float t = times[i];
  const float m  = (scal[0] + t + 1.0f) * (1.0f / 97.0f);
  const float e2 = (scal[1] + t * t + 1.0f) * (1.0f / 97.0f);
  const float alpha = 1.0f / sqrtf(e2 - m * m + 1e-5f);
  const float gma = -m * alpha;

  float pre[4], s1 = 0.f, s2 = 0.f;
  #pragma unroll
  for (int q = 0; q < 4; ++q) {
    int k = lane + q * 64;
    float p = alpha * (c_pa[k] + t * w_t[k]) + gma * c_g[k] + c_const[k]
            + alpha * wzZ[z * 256 + k];
    pre[q] = p; s1 += p; s2 += p * p;
  }
  #pragma unroll
  for (int off = 32; off; off >>= 1) {
    s1 += __shfl_xor(s1, off, 64); s2 += __shfl_xor(s2, off, 64);
  }
  float mu = s1 * (1.0f / 256.0f);
  float inv = 1.0f / sqrtf(s2 * (1.0f / 256.0f) - mu * mu + 1e-5f);
  #pragma unroll
  for (int q = 0; q < 4; ++q) {
    int k = lane + q * 64;
    h1s[w][k] = fmaxf(g1[k] * ((pre[q] - mu) * inv) + be1[k], 0.f);
  }
  __syncthreads();

  float a0 = 0.f, a1 = 0.f;
  for (int k = 0; k < 256; ++k) {
    float hv = h1s[w][k];
    a0 = fmaf(W2T[k * 128 + lane], hv, a0);
    a1 = fmaf(W2T[k * 128 + 64 + lane], hv, a1);
  }
  a0 += b2[lane]; a1 += b2[64 + lane];
  s1 = a0 + a1; s2 = a0 * a0 + a1 * a1;
  #pragma unroll
  for (int off = 32; off; off >>= 1) {
    s1 += __shfl_xor(s1, off, 64); s2 += __shfl_xor(s2, off, 64);
  }
  mu = s1 * (1.0f / 128.0f);
  inv = 1.0f / sqrtf(s2 * (1.0f / 128.0f) - mu * mu + 1e-5f);
  h2s[w][lane]      = fmaxf(g2[lane] * ((a0 - mu) * inv) + be2[lane], 0.f);
  h2s[w][64 + lane] = fmaxf(g2[64 + lane] * ((a1 - mu) * inv) + be2[64 + lane], 0.f);
  __syncthreads();

  float a3 = 0.f;
  for (int k = 0; k < 128; ++k) a3 = fmaf(W3T[k * 64 + lane], h2s[w][k], a3);
  a3 += b3[lane];
  s1 = a3; s2 = a3 * a3;
  #pragma unroll
  for (int off = 32; off; off >>= 1) {
    s1 += __shfl_xor(s1, off, 64); s2 += __shfl_xor(s2, off, 64);
  }
  mu = s1 * (1.0f / 64.0f);
  inv = 1.0f / sqrtf(s2 * (1.0f / 64.0f) - mu * mu + 1e-5f);
  h3s[w][lane] = fmaxf(g3[lane] * ((a3 - mu) * inv) + be3[lane], 0.f);
  __syncthreads();

  float a4 = 0.f;
  for (int k = 0; k < 64; ++k) a4 = fmaf(W4T[k * 64 + lane], h3s[w][k], a4);
  a4 += b4[lane];
  unsigned long long amask = adj[z];
  float predv = ((amask >> lane) & 1ull) ? a4 : -50.0f;
  out[(size_t)i * 64 + lane] = predv;
}

// ---------------- launch ----------------

extern "C" void kernel_launch(void* const* d_in, const int* in_sizes, int n_in,
                              void* d_out, int out_size, void* d_ws, size_t ws_size,
                              hipStream_t stream) {
  const float* pa    = (const float*)d_in[0];
  const float* times = (const float*)d_in[1];
  const int*   ei    = (const int*)d_in[3];
  const float* g0    = (const float*)d_in[4];
  const float* b0    = (const float*)d_in[5];
  const float* W1    = (const float*)d_in[6];
  const float* b1    = (const float*)d_in[7];
  const float* g1    = (const float*)d_in[8];
  const float* be1   = (const float*)d_in[9];
  const float* W2    = (const float*)d_in[10];
  const float* b2    = (const float*)d_in[11];
  const float* g2    = (const float*)d_in[12];
  const float* be2   = (const float*)d_in[13];
  const float* W3    = (const float*)d_in[14];
  const float* b3    = (const float*)d_in[15];
  const float* g3    = (const float*)d_in[16];
  const float* be3   = (const float*)d_in[17];
  const float* W4    = (const float*)d_in[18];
  const float* b4    = (const float*)d_in[19];

  char* ws = (char*)d_ws;
  float* c_pa    = (float*)(ws + 0);
  float* w_t     = (float*)(ws + 1024);
  float* c_g     = (float*)(ws + 2048);
  float* c_const = (float*)(ws + 3072);
  float* scal    = (float*)(ws + 4096);
  unsigned long long* adj = (unsigned long long*)(ws + 4608);
  float* wzT = (float*)(ws + 5120);                 // 64 KB
  float* wzZ = (float*)(ws + 5120 + 65536);         // 64 KB
  float* W2T = (float*)(ws + 5120 + 131072);        // 128 KB
  float* W3T = (float*)(ws + 5120 + 262144);        // 32 KB
  float* W4T = (float*)(ws + 5120 + 294912);        // 16 KB
  unsigned char* nxt  = (unsigned char*)(ws + 5120 + 311296);   // 2 MB
  unsigned char* cmap = nxt + (size_t)32768 * 64;               // 16 KB
  int* startz = (int*)(cmap + 256 * 64);                        // 1 KB
  unsigned char* zones = (unsigned char*)(startz + 256);        // 32 KB

  k_prep<<<1, 256, 0, stream>>>(pa, g0, b0, W1, b1, c_pa, w_t, c_g, c_const,
                                scal, wzT, wzZ);
  k_adj<<<1, 256, 0, stream>>>(ei, adj);
  k_tr<<<176, 256, 0, stream>>>(W2, W3, W4, W2T, W3T, W4T);
  k_pass1<<<32768, 256, 0, stream>>>(times, c_pa, w_t, c_g, c_const, scal, wzT,
                                     W2T, W3T, W4T, b2, b3, b4,
                                     g1, be1, g2, be2, g3, be3, adj, nxt);
  k_scan_a<<<256, 64, 0, stream>>>(nxt, cmap);
  k_scan_b<<<1, 64, 0, stream>>>(cmap, startz);
  k_scan_c<<<256, 64, 0, stream>>>(nxt, startz, zones);
  k_pass3<<<8192, 256, 0, stream>>>(times, zones, c_pa, w_t, c_g, c_const, scal,
                                    wzZ, W2T, W3T, W4T, b2, b3, b4,
                                    g1, be1, g2, be2, g3, be3, adj, (float*)d_out);
}

// Round 2
// 1876.182 us; speedup vs baseline: 1.8474x; 1.8474x over previous
//
#include <hip/hip_runtime.h>
#include <stdint.h>

typedef __attribute__((ext_vector_type(8))) short bf16x8;
typedef __attribute__((ext_vector_type(4))) float f32x4;

#define MFMA(a, b, c) __builtin_amdgcn_mfma_f32_16x16x32_bf16(a, b, c, 0, 0, 0)

__device__ __forceinline__ unsigned short f2b(float x) {
  unsigned u = __float_as_uint(x);
  return (unsigned short)((u + 0x7fffu + ((u >> 16) & 1u)) >> 16);
}
__device__ __forceinline__ float b2f(unsigned short h) {
  return __uint_as_float(((unsigned)h) << 16);
}

// ---------------- setup kernels ----------------

__global__ void k_prep(const float* __restrict__ pa, const float* __restrict__ g0,
                       const float* __restrict__ b0, const float* __restrict__ W1,
                       const float* __restrict__ b1,
                       float* __restrict__ c_pa, float* __restrict__ w_t,
                       float* __restrict__ c_g, float* __restrict__ c_const,
                       float* __restrict__ scal, float* __restrict__ wzT,
                       float* __restrict__ wzZ) {
  int j = threadIdx.x;  // 256 threads, one per W1 row
  const float* wr = W1 + j * 97;
  float cg = 0.f, cc = 0.f, cp = 0.f;
  for (int k = 0; k < 97; ++k) { float w = wr[k]; cg += w * g0[k]; cc += w * b0[k]; }
  for (int k = 0; k < 32; ++k) cp += wr[k] * g0[k] * pa[k];
  c_g[j] = cg;
  c_const[j] = cc + b1[j];
  c_pa[j] = cp;
  w_t[j] = wr[32] * g0[32];
  for (int z = 0; z < 64; ++z) {
    float v = wr[33 + z] * g0[33 + z];
    wzT[j * 64 + z] = v;     // [k][z]
    wzZ[z * 256 + j] = v;    // [z][k]
  }
  if (j == 0) {
    float s = 0.f, q = 0.f;
    for (int k = 0; k < 32; ++k) { float x = pa[k]; s += x; q += x * x; }
    scal[0] = s; scal[1] = q;
  }
}

__global__ void k_adj(const int* __restrict__ ei, unsigned long long* __restrict__ adj) {
  int t = threadIdx.x;  // 256
  if (t < 64) adj[t] = 1ull << t;   // self loops (overwrites stale state each call)
  __syncthreads();
  int u = ei[t] & 63, v = ei[256 + t] & 63;
  atomicOr(&adj[u], 1ull << v);
  atomicOr(&adj[v], 1ull << u);
}

__global__ void k_tr(const float* __restrict__ W2, const float* __restrict__ W3,
                     const float* __restrict__ W4,
                     float* __restrict__ W2T, float* __restrict__ W3T,
                     float* __restrict__ W4T) {
  int idx = blockIdx.x * 256 + threadIdx.x;
  if (idx < 32768) {                     // W2 [128,256] -> W2T [256,128]
    int k = idx >> 7, j = idx & 127;
    W2T[idx] = W2[j * 256 + k];
  } else if (idx < 40960) {              // W3 [64,128] -> W3T [128,64]
    int r = idx - 32768; int k = r >> 6, j = r & 63;
    W3T[r] = W3[j * 128 + k];
  } else if (idx < 45056) {              // W4 [64,64] -> W4T [64,64]
    int r = idx - 40960; int k = r >> 6, j = r & 63;
    W4T[r] = W4[j * 64 + k];
  }
}

// Pre-split weights into MFMA A-fragment order, bf16 hi/lo.
// A-frag (16x16x32): elem j of lane l = A[mt*16 + (l&15)][kt*32 + (l>>4)*8 + j]
__global__ void k_wsplit(const float* __restrict__ W2, const float* __restrict__ W3,
                         const float* __restrict__ W4,
                         unsigned short* __restrict__ W2Ah, unsigned short* __restrict__ W2Al,
                         unsigned short* __restrict__ W3Ah, unsigned short* __restrict__ W3Al,
                         unsigned short* __restrict__ W4Ah, unsigned short* __restrict__ W4Al) {
  int idx = blockIdx.x * 256 + threadIdx.x;
  float w; unsigned short* ph; unsigned short* pl; int o;
  if (idx < 32768) {                       // W2 [128][256]: mt 0..7, kt 0..7
    int mt = idx >> 12, kt = (idx >> 9) & 7, lane = (idx >> 3) & 63, j = idx & 7;
    int m = mt * 16 + (lane & 15), k = kt * 32 + (lane >> 4) * 8 + j;
    w = W2[m * 256 + k]; ph = W2Ah; pl = W2Al; o = idx;
  } else if (idx < 40960) {                // W3 [64][128]: mt 0..3, kt 0..3
    int r = idx - 32768;
    int mt = r >> 11, kt = (r >> 9) & 3, lane = (r >> 3) & 63, j = r & 7;
    int m = mt * 16 + (lane & 15), k = kt * 32 + (lane >> 4) * 8 + j;
    w = W3[m * 128 + k]; ph = W3Ah; pl = W3Al; o = r;
  } else if (idx < 45056) {                // W4 [64][64]: mt 0..3, kt 0..1
    int r = idx - 40960;
    int mt = r >> 10, kt = (r >> 9) & 1, lane = (r >> 3) & 63, j = r & 7;
    int m = mt * 16 + (lane & 15), k = kt * 32 + (lane >> 4) * 8 + j;
    w = W4[m * 64 + k]; ph = W4Ah; pl = W4Al; o = r;
  } else return;
  unsigned short hb = f2b(w);
  ph[o] = hb;
  pl[o] = f2b(w - b2f(hb));
}

// ---------------- pass 1: transition table next[i][z], MFMA split-bf16 ----------------

__global__ __launch_bounds__(256, 2) void k_pass1(
    const float* __restrict__ times,
    const float* __restrict__ c_pa, const float* __restrict__ w_t,
    const float* __restrict__ c_g, const float* __restrict__ c_const,
    const float* __restrict__ scal, const float* __restrict__ wzT,
    const unsigned short* __restrict__ W2Ah, const unsigned short* __restrict__ W2Al,
    const unsigned short* __restrict__ W3Ah, const unsigned short* __restrict__ W3Al,
    const unsigned short* __restrict__ W4Ah, const unsigned short* __restrict__ W4Al,
    const float* __restrict__ b2, const float* __restrict__ b3,
    const float* __restrict__ b4,
    const float* __restrict__ g1, const float* __restrict__ be1,
    const float* __restrict__ g2, const float* __restrict__ be2,
    const float* __restrict__ g3, const float* __restrict__ be3,
    const unsigned long long* __restrict__ adj,
    unsigned char* __restrict__ nxt) {
  // region0: B1 chunk frags (2x16KB) -> reused as h2p fp32 [128][66]
  // region1: B2 frags (2x16KB) -> reused as h3p [64][66] + B3 frags (2x8KB)
  __shared__ __align__(16) char region0[33792];
  __shared__ __align__(16) char region1[33280];
  __shared__ float ps1[256], ps2[256];
  __shared__ unsigned long long pk[256];

  unsigned short* B1hi = (unsigned short*)region0;            // [4kt][4nt][64][8]
  unsigned short* B1lo = (unsigned short*)(region0 + 16384);
  float* h2p = (float*)region0;                               // [128][66]
  unsigned short* B2hi = (unsigned short*)region1;            // [4][4][64][8]
  unsigned short* B2lo = (unsigned short*)(region1 + 16384);
  float* h3p = (float*)region1;                               // [64][66]
  unsigned short* B3hi = (unsigned short*)(region1 + 16896);  // [2][4][64][8]
  unsigned short* B3lo = (unsigned short*)(region1 + 16896 + 8192);

  const int tid = threadIdx.x;
  const int lane = tid & 63;          // lane == zone z for producer phases
  const int l15 = lane & 15;
  const int lhi = lane >> 4;
  const int w = __builtin_amdgcn_readfirstlane(tid >> 6);
  const int i = blockIdx.x;

  const float t = times[i];
  const float m0 = (scal[0] + t + 1.0f) * (1.0f / 97.0f);
  const float e2 = (scal[1] + t * t + 1.0f) * (1.0f / 97.0f);
  const float alpha = 1.0f / sqrtf(e2 - m0 * m0 + 1e-5f);
  const float gma = -m0 * alpha;

  const f32x4 zero4 = {0.f, 0.f, 0.f, 0.f};

  // ---- phase A: LN1 statistics (per column z = lane) ----
  float s1 = 0.f, s2 = 0.f;
  for (int kk = 0; kk < 64; ++kk) {
    int k = w * 64 + kk;
    float u = fmaf(t, w_t[k], c_pa[k]);
    u = fmaf(alpha, u, c_const[k]);
    u = fmaf(gma, c_g[k], u);
    float p = fmaf(alpha, wzT[k * 64 + lane], u);
    s1 += p; s2 += p * p;
  }
  ps1[w * 64 + lane] = s1;
  ps2[w * 64 + lane] = s2;
  __syncthreads();
  float mu1, inv1;
  {
    float a = ps1[lane] + ps1[64 + lane] + ps1[128 + lane] + ps1[192 + lane];
    float b = ps2[lane] + ps2[64 + lane] + ps2[128 + lane] + ps2[192 + lane];
    mu1 = a * (1.0f / 256.0f);
    inv1 = 1.0f / sqrtf(b * (1.0f / 256.0f) - mu1 * mu1 + 1e-5f);
  }

  // ---- GEMM1: h2[128][64] = W2 @ h1, K=256 in 2 chunks of 128 ----
  f32x4 acc[2][4];
  #pragma unroll
  for (int a = 0; a < 2; ++a)
    #pragma unroll
    for (int b = 0; b < 4; ++b) acc[a][b] = zero4;

  for (int kc = 0; kc < 2; ++kc) {
    __syncthreads();   // previous chunk's MFMA readers done
    // producers: h1 for k in [kc*128+32w, +32), split to bf16 hi/lo frag layout
    #pragma unroll
    for (int q = 0; q < 4; ++q) {
      int kbase = kc * 128 + w * 32 + q * 8;
      bf16x8 vh, vl;
      #pragma unroll
      for (int j = 0; j < 8; ++j) {
        int k = kbase + j;
        float u = fmaf(t, w_t[k], c_pa[k]);
        u = fmaf(alpha, u, c_const[k]);
        u = fmaf(gma, c_g[k], u);
        float p = fmaf(alpha, wzT[k * 64 + lane], u);
        float h = fmaxf(fmaf(g1[k], (p - mu1) * inv1, be1[k]), 0.f);
        unsigned short hb = f2b(h);
        vh[j] = (short)hb;
        vl[j] = (short)f2b(h - b2f(hb));
      }
      int slot = ((w * 4 + lhi) * 64 + q * 16 + l15) * 8;
      *(bf16x8*)(B1hi + slot) = vh;
      *(bf16x8*)(B1lo + slot) = vl;
    }
    __syncthreads();
    // MFMA: wave owns M rows [32w, 32w+32)
    for (int kt = 0; kt < 4; ++kt) {
      int ktg = kc * 4 + kt;
      bf16x8 a0h = *(const bf16x8*)(W2Ah + (((2 * w + 0) * 8 + ktg) * 64 + lane) * 8);
      bf16x8 a0l = *(const bf16x8*)(W2Al + (((2 * w + 0) * 8 + ktg) * 64 + lane) * 8);
      bf16x8 a1h = *(const bf16x8*)(W2Ah + (((2 * w + 1) * 8 + ktg) * 64 + lane) * 8);
      bf16x8 a1l = *(const bf16x8*)(W2Al + (((2 * w + 1) * 8 + ktg) * 64 + lane) * 8);
      #pragma unroll
      for (int nt = 0; nt < 4; ++nt) {
        bf16x8 bh = *(const bf16x8*)(B1hi + ((kt * 4 + nt) * 64 + lane) * 8);
        bf16x8 bl = *(const bf16x8*)(B1lo + ((kt * 4 + nt) * 64 + lane) * 8);
        acc[0][nt] = MFMA(a0h, bh, acc[0][nt]);
        acc[0][nt] = MFMA(a0h, bl, acc[0][nt]);
        acc[0][nt] = MFMA(a0l, bh, acc[0][nt]);
        acc[1][nt] = MFMA(a1h, bh, acc[1][nt]);
        acc[1][nt] = MFMA(a1h, bl, acc[1][nt]);
        acc[1][nt] = MFMA(a1l, bh, acc[1][nt]);
      }
    }
  }
  // +b2, LN2 stats (over 128 rows, per column)
  #pragma unroll
  for (int mti = 0; mti < 2; ++mti) {
    f32x4 bv = *(const f32x4*)(b2 + w * 32 + mti * 16 + lhi * 4);
    #pragma unroll
    for (int nt = 0; nt < 4; ++nt) acc[mti][nt] += bv;
  }
  {
    float sa[4], sb[4];
    #pragma unroll
    for (int nt = 0; nt < 4; ++nt) {
      float x1 = 0.f, x2 = 0.f;
      #pragma unroll
      for (int mti = 0; mti < 2; ++mti)
        #pragma unroll
        for (int r = 0; r < 4; ++r) { float v = acc[mti][nt][r]; x1 += v; x2 += v * v; }
      x1 += __shfl_xor(x1, 16, 64); x1 += __shfl_xor(x1, 32, 64);
      x2 += __shfl_xor(x2, 16, 64); x2 += __shfl_xor(x2, 32, 64);
      sa[nt] = x1; sb[nt] = x2;
    }
    if (lane < 16) {
      #pragma unroll
      for (int nt = 0; nt < 4; ++nt) {
        ps1[w * 64 + nt * 16 + lane] = sa[nt];
        ps2[w * 64 + nt * 16 + lane] = sb[nt];
      }
    }
  }
  __syncthreads();            // all MFMAs done: region0 reusable, ps visible
  #pragma unroll
  for (int mti = 0; mti < 2; ++mti)
    #pragma unroll
    for (int nt = 0; nt < 4; ++nt)
      #pragma unroll
      for (int r = 0; r < 4; ++r)
        h2p[(w * 32 + mti * 16 + lhi * 4 + r) * 66 + nt * 16 + l15] = acc[mti][nt][r];
  __syncthreads();

  // ---- B2 producers: LN2 + relu + split ----
  float mu2, inv2;
  {
    float a = ps1[lane] + ps1[64 + lane] + ps1[128 + lane] + ps1[192 + lane];
    float b = ps2[lane] + ps2[64 + lane] + ps2[128 + lane] + ps2[192 + lane];
    mu2 = a * (1.0f / 128.0f);
    inv2 = 1.0f / sqrtf(b * (1.0f / 128.0f) - mu2 * mu2 + 1e-5f);
  }
  #pragma unroll
  for (int q = 0; q < 4; ++q) {
    int mb = w * 32 + q * 8;
    bf16x8 vh, vl;
    #pragma unroll
    for (int j = 0; j < 8; ++j) {
      int mm = mb + j;
      float v = h2p[mm * 66 + lane];
      float h = fmaxf(fmaf(g2[mm], (v - mu2) * inv2, be2[mm]), 0.f);
      unsigned short hb = f2b(h);
      vh[j] = (short)hb;
      vl[j] = (short)f2b(h - b2f(hb));
    }
    int slot = ((w * 4 + lhi) * 64 + q * 16 + l15) * 8;
    *(bf16x8*)(B2hi + slot) = vh;
    *(bf16x8*)(B2lo + slot) = vl;
  }
  __syncthreads();

  // ---- GEMM2: h3[64][64] = W3 @ h2, wave owns rows [16w, 16w+16) ----
  f32x4 acc2[4];
  #pragma unroll
  for (int b = 0; b < 4; ++b) acc2[b] = zero4;
  for (int kt = 0; kt < 4; ++kt) {
    bf16x8 ah = *(const bf16x8*)(W3Ah + ((w * 4 + kt) * 64 + lane) * 8);
    bf16x8 al = *(const bf16x8*)(W3Al + ((w * 4 + kt) * 64 + lane) * 8);
    #pragma unroll
    for (int nt = 0; nt < 4; ++nt) {
      bf16x8 bh = *(const bf16x8*)(B2hi + ((kt * 4 + nt) * 64 + lane) * 8);
      bf16x8 bl = *(const bf16x8*)(B2lo + ((kt * 4 + nt) * 64 + lane) * 8);
      acc2[nt] = MFMA(ah, bh, acc2[nt]);
      acc2[nt] = MFMA(ah, bl, acc2[nt]);
      acc2[nt] = MFMA(al, bh, acc2[nt]);
    }
  }
  {
    f32x4 bv = *(const f32x4*)(b3 + w * 16 + lhi * 4);
    #pragma unroll
    for (int nt = 0; nt < 4; ++nt) acc2[nt] += bv;
  }
  {
    float sa[4], sb[4];
    #pragma unroll
    for (int nt = 0; nt < 4; ++nt) {
      float x1 = 0.f, x2 = 0.f;
      #pragma unroll
      for (int r = 0; r < 4; ++r) { float v = acc2[nt][r]; x1 += v; x2 += v * v; }
      x1 += __shfl_xor(x1, 16, 64); x1 += __shfl_xor(x1, 32, 64);
      x2 += __shfl_xor(x2, 16, 64); x2 += __shfl_xor(x2, 32, 64);
      sa[nt] = x1; sb[nt] = x2;
    }
    if (lane < 16) {
      #pragma unroll
      for (int nt = 0; nt < 4; ++nt) {
        ps1[w * 64 + nt * 16 + lane] = sa[nt];
        ps2[w * 64 + nt * 16 + lane] = sb[nt];
      }
    }
  }
  __syncthreads();            // B2 frags free, ps visible
  #pragma unroll
  for (int nt = 0; nt < 4; ++nt)
    #pragma unroll
    for (int r = 0; r < 4; ++r)
      h3p[(w * 16 + lhi * 4 + r) * 66 + nt * 16 + l15] = acc2[nt][r];
  __syncthreads();

  // ---- B3 producers: LN3 + relu + split ----
  float mu3, inv3;
  {
    float a = ps1[lane] + ps1[64 + lane] + ps1[128 + lane] + ps1[192 + lane];
    float b = ps2[lane] + ps2[64 + lane] + ps2[128 + lane] + ps2[192 + lane];
    mu3 = a * (1.0f / 64.0f);
    inv3 = 1.0f / sqrtf(b * (1.0f / 64.0f) - mu3 * mu3 + 1e-5f);
  }
  #pragma unroll
  for (int q = 0; q < 2; ++q) {
    int o = w * 2 + q;        // octet 0..7
    int mb = o * 8;
    bf16x8 vh, vl;
    #pragma unroll
    for (int j = 0; j < 8; ++j) {
      int mm = mb + j;
      float v = h3p[mm * 66 + lane];
      float h = fmaxf(fmaf(g3[mm], (v - mu3) * inv3, be3[mm]), 0.f);
      unsigned short hb = f2b(h);
      vh[j] = (short)hb;
      vl[j] = (short)f2b(h - b2f(hb));
    }
    int slot = (((o >> 2) * 4 + lhi) * 64 + (o & 3) * 16 + l15) * 8;
    *(bf16x8*)(B3hi + slot) = vh;
    *(bf16x8*)(B3lo + slot) = vl;
  }
  __syncthreads();

  // ---- GEMM3: raw[64][64] = W4 @ h3, wave owns outputs [16w, 16w+16) ----
  f32x4 acc3[4];
  #pragma unroll
  for (int b = 0; b < 4; ++b) acc3[b] = zero4;
  for (int kt = 0; kt < 2; ++kt) {
    bf16x8 ah = *(const bf16x8*)(W4Ah + ((w * 2 + kt) * 64 + lane) * 8);
    bf16x8 al = *(const bf16x8*)(W4Al + ((w * 2 + kt) * 64 + lane) * 8);
    #pragma unroll
    for (int nt = 0; nt < 4; ++nt) {
      bf16x8 bh = *(const bf16x8*)(B3hi + ((kt * 4 + nt) * 64 + lane) * 8);
      bf16x8 bl = *(const bf16x8*)(B3lo + ((kt * 4 + nt) * 64 + lane) * 8);
      acc3[nt] = MFMA(ah, bh, acc3[nt]);
      acc3[nt] = MFMA(ah, bl, acc3[nt]);
      acc3[nt] = MFMA(al, bh, acc3[nt]);
    }
  }
  // epilogue: +b4, mask by adjacency, argmax keys
  f32x4 b4v = *(const f32x4*)(b4 + w * 16 + lhi * 4);
  unsigned long long kbest[4];
  #pragma unroll
  for (int nt = 0; nt < 4; ++nt) {
    unsigned long long am = adj[nt * 16 + l15];
    unsigned long long kb = 0ull;
    #pragma unroll
    for (int r = 0; r < 4; ++r) {
      int o = w * 16 + lhi * 4 + r;
      float raw = acc3[nt][r] + b4v[r];
      float val = ((am >> o) & 1ull) ? raw : -__builtin_huge_valf();
      unsigned u = __float_as_uint(val);
      u = (u & 0x80000000u) ? ~u : (u | 0x80000000u);   // order-preserving map
      unsigned long long key = ((unsigned long long)u << 6) | (unsigned long long)(63 - o);
      if (key > kb) kb = key;                            // ties -> lowest o
    }
    unsigned long long oth = __shfl_xor(kb, 16, 64); if (oth > kb) kb = oth;
    oth = __shfl_xor(kb, 32, 64); if (oth > kb) kb = oth;
    kbest[nt] = kb;
  }
  if (lane < 16) {
    #pragma unroll
    for (int nt = 0; nt < 4; ++nt) pk[w * 64 + nt * 16 + lane] = kbest[nt];
  }
  __syncthreads();
  if (tid < 64) {
    unsigned long long k0 = pk[tid], k1 = pk[64 + tid];
    unsigned long long k2 = pk[128 + tid], k3 = pk[192 + tid];
    unsigned long long a = k0 > k1 ? k0 : k1;
    unsigned long long b = k2 > k3 ? k2 : k3;
    unsigned long long bb = a > b ? a : b;
    nxt[(size_t)i * 64 + tid] = (unsigned char)(63u - (unsigned)(bb & 63ull));
  }
}

// ---------------- trajectory via parallel map-composition scan ----------------

__global__ void k_scan_a(const unsigned char* __restrict__ nxt,
                         unsigned char* __restrict__ cmap) {
  int c = blockIdx.x, lane = threadIdx.x;  // 64 threads
  int g = lane;                            // identity map
  const unsigned char* p = nxt + (size_t)c * 128 * 64;
  for (int s = 0; s < 128; ++s) {
    int sig = p[s * 64 + lane];
    g = __shfl(sig, g, 64);
  }
  cmap[c * 64 + lane] = (unsigned char)g;
}

__global__ void k_scan_b(const unsigned char* __restrict__ cmap,
                         int* __restrict__ startz) {
  int lane = threadIdx.x;
  int cur = 0;
  for (int c = 0; c < 256; ++c) {
    if (lane == 0) startz[c] = cur;
    int row = cmap[c * 64 + lane];
    cur = __shfl(row, cur, 64);
  }
}

__global__ void k_scan_c(const unsigned char* __restrict__ nxt,
                         const int* __restrict__ startz,
                         unsigned char* __restrict__ zones) {
  int c = blockIdx.x, lane = threadIdx.x;
  int cur = startz[c];
  const unsigned char* p = nxt + (size_t)c * 128 * 64;
  for (int s = 0; s < 128; ++s) {
    if (lane == 0) zones[c * 128 + s] = (unsigned char)cur;
    int row = p[s * 64 + lane];
    cur = __shfl(row, cur, 64);
  }
}

// ---------------- pass 3: logits for the actual zone at each step ----------------

__global__ void k_pass3(
    const float* __restrict__ times, const unsigned char* __restrict__ zones,
    const float* __restrict__ c_pa, const float* __restrict__ w_t,
    const float* __restrict__ c_g, const float* __restrict__ c_const,
    const float* __restrict__ scal, const float* __restrict__ wzZ,
    const float* __restrict__ W2T, const float* __restrict__ W3T,
    const float* __restrict__ W4T,
    const float* __restrict__ b2, const float* __restrict__ b3,
    const float* __restrict__ b4,
    const float* __restrict__ g1, const float* __restrict__ be1,
    const float* __restrict__ g2, const float* __restrict__ be2,
    const float* __restrict__ g3, const float* __restrict__ be3,
    const unsigned long long* __restrict__ adj,
    float* __restrict__ out) {
  __shared__ float h1s[4][256];
  __shared__ float h2s[4][128];
  __shared__ float h3s[4][64];
  const int tid = threadIdx.x, lane = tid & 63, w = tid >> 6;
  const int i = blockIdx.x * 4 + w;            // one timestep per wave
  const int z = zones[i];
  const float t = times[i];
  const float m  = (scal[0] + t + 1.0f) * (1.0f / 97.0f);
  const float e2 = (scal[1] + t * t + 1.0f) * (1.0f / 97.0f);
  const float alpha = 1.0f / sqrtf(e2 - m * m + 1e-5f);
  const float gma = -m * alpha;

  float pre[4], s1 = 0.f, s2 = 0.f;
  #pragma unroll
  for (int q = 0; q < 4; ++q) {
    int k = lane + q * 64;
    float p = alpha * (c_pa[k] + t * w_t[k]) + gma * c_g[k] + c_const[k]
            + alpha * wzZ[z * 256 + k];
    pre[q] = p; s1 += p; s2 += p * p;
  }
  #pragma unroll
  for (int off = 32; off; off >>= 1) {
    s1 += __shfl_xor(s1, off, 64); s2 += __shfl_xor(s2, off, 64);
  }
  float mu = s1 * (1.0f / 256.0f);
  float inv = 1.0f / sqrtf(s2 * (1.0f / 256.0f) - mu * mu + 1e-5f);
  #pragma unroll
  for (int q = 0; q < 4; ++q) {
    int k = lane + q * 64;
    h1s[w][k] = fmaxf(g1[k] * ((pre[q] - mu) * inv) + be1[k], 0.f);
  }
  __syncthreads();

  float a0 = 0.f, a1 = 0.f;
  for (int k = 0; k < 256; ++k) {
    float hv = h1s[w][k];
    a0 = fmaf(W2T[k * 128 + lane], hv, a0);
    a1 = fmaf(W2T[k * 128 + 64 + lane], hv, a1);
  }
  a0 += b2[lane]; a1 += b2[64 + lane];
  s1 = a0 + a1; s2 = a0 * a0 + a1 * a1;
  #pragma unroll
  for (int off = 32; off; off >>= 1) {
    s1 += __shfl_xor(s1, off, 64); s2 += __shfl_xor(s2, off, 64);
  }
  mu = s1 * (1.0f / 128.0f);
  inv = 1.0f / sqrtf(s2 * (1.0f / 128.0f) - mu * mu + 1e-5f);
  h2s[w][lane]      = fmaxf(g2[lane] * ((a0 - mu) * inv) + be2[lane], 0.f);
  h2s[w][64 + lane] = fmaxf(g2[64 + lane] * ((a1 - mu) * inv) + be2[64 + lane], 0.f);
  __syncthreads();

  float a3 = 0.f;
  for (int k = 0; k < 128; ++k) a3 = fmaf(W3T[k * 64 + lane], h2s[w][k], a3);
  a3 += b3[lane];
  s1 = a3; s2 = a3 * a3;
  #pragma unroll
  for (int off = 32; off; off >>= 1) {
    s1 += __shfl_xor(s1, off, 64); s2 += __shfl_xor(s2, off, 64);
  }
  mu = s1 * (1.0f / 64.0f);
  inv = 1.0f / sqrtf(s2 * (1.0f / 64.0f) - mu * mu + 1e-5f);
  h3s[w][lane] = fmaxf(g3[lane] * ((a3 - mu) * inv) + be3[lane], 0.f);
  __syncthreads();

  float a4 = 0.f;
  for (int k = 0; k < 64; ++k) a4 = fmaf(W4T[k * 64 + lane], h3s[w][k], a4);
  a4 += b4[lane];
  unsigned long long amask = adj[z];
  float predv = ((amask >> lane) & 1ull) ? a4 : -50.0f;
  out[(size_t)i * 64 + lane] = predv;
}

// ---------------- launch ----------------

extern "C" void kernel_launch(void* const* d_in, const int* in_sizes, int n_in,
                              void* d_out, int out_size, void* d_ws, size_t ws_size,
                              hipStream_t stream) {
  const float* pa    = (const float*)d_in[0];
  const float* times = (const float*)d_in[1];
  const int*   ei    = (const int*)d_in[3];
  const float* g0    = (const float*)d_in[4];
  const float* b0    = (const float*)d_in[5];
  const float* W1    = (const float*)d_in[6];
  const float* b1    = (const float*)d_in[7];
  const float* g1    = (const float*)d_in[8];
  const float* be1   = (const float*)d_in[9];
  const float* W2    = (const float*)d_in[10];
  const float* b2    = (const float*)d_in[11];
  const float* g2    = (const float*)d_in[12];
  const float* be2   = (const float*)d_in[13];
  const float* W3    = (const float*)d_in[14];
  const float* b3    = (const float*)d_in[15];
  const float* g3    = (const float*)d_in[16];
  const float* be3   = (const float*)d_in[17];
  const float* W4    = (const float*)d_in[18];
  const float* b4    = (const float*)d_in[19];

  char* ws = (char*)d_ws;
  float* c_pa    = (float*)(ws + 0);
  float* w_t     = (float*)(ws + 1024);
  float* c_g     = (float*)(ws + 2048);
  float* c_const = (float*)(ws + 3072);
  float* scal    = (float*)(ws + 4096);
  unsigned long long* adj = (unsigned long long*)(ws + 4608);
  float* wzT = (float*)(ws + 5120);                   // 64 KB
  float* wzZ = (float*)(ws + 70656);                  // 64 KB
  float* W2T = (float*)(ws + 136192);                 // 128 KB
  float* W3T = (float*)(ws + 267264);                 // 32 KB
  float* W4T = (float*)(ws + 300032);                 // 16 KB
  unsigned short* W2Ah = (unsigned short*)(ws + 316416);  // 64 KB
  unsigned short* W2Al = (unsigned short*)(ws + 381952);  // 64 KB
  unsigned short* W3Ah = (unsigned short*)(ws + 447488);  // 16 KB
  unsigned short* W3Al = (unsigned short*)(ws + 463872);  // 16 KB
  unsigned short* W4Ah = (unsigned short*)(ws + 480256);  // 8 KB
  unsigned short* W4Al = (unsigned short*)(ws + 488448);  // 8 KB
  unsigned char* nxt  = (unsigned char*)(ws + 496640);    // 2 MB
  unsigned char* cmap = (unsigned char*)(ws + 2593792);   // 16 KB
  int* startz = (int*)(ws + 2610176);                     // 1 KB
  unsigned char* zones = (unsigned char*)(ws + 2611200);  // 32 KB

  k_prep<<<1, 256, 0, stream>>>(pa, g0, b0, W1, b1, c_pa, w_t, c_g, c_const,
                                scal, wzT, wzZ);
  k_adj<<<1, 256, 0, stream>>>(ei, adj);
  k_tr<<<176, 256, 0, stream>>>(W2, W3, W4, W2T, W3T, W4T);
  k_wsplit<<<176, 256, 0, stream>>>(W2, W3, W4, W2Ah, W2Al, W3Ah, W3Al, W4Ah, W4Al);
  k_pass1<<<32768, 256, 0, stream>>>(times, c_pa, w_t, c_g, c_const, scal, wzT,
                                     W2Ah, W2Al, W3Ah, W3Al, W4Ah, W4Al,
                                     b2, b3, b4, g1, be1, g2, be2, g3, be3,
                                     adj, nxt);
  k_scan_a<<<256, 64, 0, stream>>>(nxt, cmap);
  k_scan_b<<<1, 64, 0, stream>>>(cmap, startz);
  k_scan_c<<<256, 64, 0, stream>>>(nxt, startz, zones);
  k_pass3<<<8192, 256, 0, stream>>>(times, zones, c_pa, w_t, c_g, c_const, scal,
                                    wzZ, W2T, W3T, W4T, b2, b3, b4,
                                    g1, be1, g2, be2, g3, be3, adj, (float*)d_out);
}

// Round 3
// 1030.856 us; speedup vs baseline: 3.3624x; 1.8200x over previous
//
#include <hip/hip_runtime.h>
#include <stdint.h>

typedef __attribute__((ext_vector_type(8))) short bf16x8;
typedef __attribute__((ext_vector_type(4))) float f32x4;

#define MFMA(a, b, c) __builtin_amdgcn_mfma_f32_16x16x32_bf16(a, b, c, 0, 0, 0)

__device__ __forceinline__ unsigned short f2b(float x) {
  unsigned u = __float_as_uint(x);
  return (unsigned short)((u + 0x7fffu + ((u >> 16) & 1u)) >> 16);
}
__device__ __forceinline__ float b2f(unsigned short h) {
  return __uint_as_float(((unsigned)h) << 16);
}

// scratch swizzle: spreads the 4-row (lhi) dimension across banks; identical
// function on write (col = nt*16+l15) and read (col = lane), keyed on row bits
#define SWZ(row, col) ((col) ^ ((((row) >> 2) & 1) << 4) ^ ((((row) >> 3) & 1) << 2))

// ---------------- setup kernels ----------------

__global__ void k_prep(const float* __restrict__ pa, const float* __restrict__ g0,
                       const float* __restrict__ b0, const float* __restrict__ W1,
                       const float* __restrict__ b1,
                       float* __restrict__ c_pa, float* __restrict__ w_t,
                       float* __restrict__ c_g, float* __restrict__ c_const,
                       float* __restrict__ scal, float* __restrict__ wzT,
                       float* __restrict__ wzZ) {
  int j = threadIdx.x;  // 256 threads, one per W1 row
  const float* wr = W1 + j * 97;
  float cg = 0.f, cc = 0.f, cp = 0.f;
  for (int k = 0; k < 97; ++k) { float w = wr[k]; cg += w * g0[k]; cc += w * b0[k]; }
  for (int k = 0; k < 32; ++k) cp += wr[k] * g0[k] * pa[k];
  c_g[j] = cg;
  c_const[j] = cc + b1[j];
  c_pa[j] = cp;
  w_t[j] = wr[32] * g0[32];
  for (int z = 0; z < 64; ++z) {
    float v = wr[33 + z] * g0[33 + z];
    wzT[j * 64 + z] = v;     // [k][z]
    wzZ[z * 256 + j] = v;    // [z][k]
  }
  if (j == 0) {
    float s = 0.f, q = 0.f;
    for (int k = 0; k < 32; ++k) { float x = pa[k]; s += x; q += x * x; }
    scal[0] = s; scal[1] = q;
  }
}

// closed-form LN1 stat tables: per z, A1=sum_k wz, Q=sum wz^2, and dot
// products of wz-column with the 4 u-coefficient vectors
__global__ void k_prep2(const float* __restrict__ c_pa, const float* __restrict__ w_t,
                        const float* __restrict__ c_g, const float* __restrict__ c_const,
                        const float* __restrict__ wzT, float* __restrict__ st) {
  int z = threadIdx.x;  // 64
  float A = 0.f, Q = 0.f, dpa = 0.f, dwt = 0.f, dcg = 0.f, dcc = 0.f;
  for (int k = 0; k < 256; ++k) {
    float wz = wzT[k * 64 + z];
    A += wz; Q = fmaf(wz, wz, Q);
    dpa = fmaf(c_pa[k], wz, dpa);
    dwt = fmaf(w_t[k], wz, dwt);
    dcg = fmaf(c_g[k], wz, dcg);
    dcc = fmaf(c_const[k], wz, dcc);
  }
  st[z] = A; st[64 + z] = Q; st[128 + z] = dpa;
  st[192 + z] = dwt; st[256 + z] = dcg; st[320 + z] = dcc;
}

__global__ void k_adj(const int* __restrict__ ei, unsigned long long* __restrict__ adj) {
  int t = threadIdx.x;  // 256
  if (t < 64) adj[t] = 1ull << t;   // self loops (overwrites stale state each call)
  __syncthreads();
  int u = ei[t] & 63, v = ei[256 + t] & 63;
  atomicOr(&adj[u], 1ull << v);
  atomicOr(&adj[v], 1ull << u);
}

__global__ void k_tr(const float* __restrict__ W2, const float* __restrict__ W3,
                     const float* __restrict__ W4,
                     float* __restrict__ W2T, float* __restrict__ W3T,
                     float* __restrict__ W4T) {
  int idx = blockIdx.x * 256 + threadIdx.x;
  if (idx < 32768) {                     // W2 [128,256] -> W2T [256,128]
    int k = idx >> 7, j = idx & 127;
    W2T[idx] = W2[j * 256 + k];
  } else if (idx < 40960) {              // W3 [64,128] -> W3T [128,64]
    int r = idx - 32768; int k = r >> 6, j = r & 63;
    W3T[r] = W3[j * 128 + k];
  } else if (idx < 45056) {              // W4 [64,64] -> W4T [64,64]
    int r = idx - 40960; int k = r >> 6, j = r & 63;
    W4T[r] = W4[j * 64 + k];
  }
}

// Pre-split weights into MFMA A-fragment order, bf16 hi/lo.
// A-frag (16x16x32): elem j of lane l = A[mt*16 + (l&15)][kt*32 + (l>>4)*8 + j]
__global__ void k_wsplit(const float* __restrict__ W2, const float* __restrict__ W3,
                         const float* __restrict__ W4,
                         unsigned short* __restrict__ W2Ah, unsigned short* __restrict__ W2Al,
                         unsigned short* __restrict__ W3Ah, unsigned short* __restrict__ W3Al,
                         unsigned short* __restrict__ W4Ah, unsigned short* __restrict__ W4Al) {
  int idx = blockIdx.x * 256 + threadIdx.x;
  float w; unsigned short* ph; unsigned short* pl; int o;
  if (idx < 32768) {                       // W2 [128][256]: mt 0..7, kt 0..7
    int mt = idx >> 12, kt = (idx >> 9) & 7, lane = (idx >> 3) & 63, j = idx & 7;
    int m = mt * 16 + (lane & 15), k = kt * 32 + (lane >> 4) * 8 + j;
    w = W2[m * 256 + k]; ph = W2Ah; pl = W2Al; o = idx;
  } else if (idx < 40960) {                // W3 [64][128]: mt 0..3, kt 0..3
    int r = idx - 32768;
    int mt = r >> 11, kt = (r >> 9) & 3, lane = (r >> 3) & 63, j = r & 7;
    int m = mt * 16 + (lane & 15), k = kt * 32 + (lane >> 4) * 8 + j;
    w = W3[m * 128 + k]; ph = W3Ah; pl = W3Al; o = r;
  } else if (idx < 45056) {                // W4 [64][64]: mt 0..3, kt 0..1
    int r = idx - 40960;
    int mt = r >> 10, kt = (r >> 9) & 1, lane = (r >> 3) & 63, j = r & 7;
    int m = mt * 16 + (lane & 15), k = kt * 32 + (lane >> 4) * 8 + j;
    w = W4[m * 64 + k]; ph = W4Ah; pl = W4Al; o = r;
  } else return;
  unsigned short hb = f2b(w);
  ph[o] = hb;
  pl[o] = f2b(w - b2f(hb));
}

// ---------------- pass 1: transition table next[i][z], MFMA split-bf16 ----------------

__global__ __launch_bounds__(256, 4) void k_pass1(
    const float* __restrict__ times,
    const float* __restrict__ c_pa, const float* __restrict__ w_t,
    const float* __restrict__ c_g, const float* __restrict__ c_const,
    const float* __restrict__ wzT, const float* __restrict__ st,
    const unsigned short* __restrict__ W2Ah, const unsigned short* __restrict__ W2Al,
    const unsigned short* __restrict__ W3Ah, const unsigned short* __restrict__ W3Al,
    const unsigned short* __restrict__ W4Ah, const unsigned short* __restrict__ W4Al,
    const float* __restrict__ b2, const float* __restrict__ b3,
    const float* __restrict__ b4,
    const float* __restrict__ g1, const float* __restrict__ be1,
    const float* __restrict__ g2, const float* __restrict__ be2,
    const float* __restrict__ g3, const float* __restrict__ be3,
    const unsigned long long* __restrict__ adj,
    unsigned char* __restrict__ nxt) {
  // one 32KB region aliased through the pipeline:
  //   B1 frags (2x16KB) -> h2p fp32 [128][64] swz -> B2 frags -> h3p [64][64] + B3 frags
  __shared__ __align__(16) char region[32768];
  __shared__ float u_lds[256];
  __shared__ float ps1[256], ps2[256];
  __shared__ unsigned long long pk[256];

  unsigned short* B1hi = (unsigned short*)region;
  unsigned short* B1lo = (unsigned short*)(region + 16384);
  float* h2p = (float*)region;                         // [128][64] swizzled
  unsigned short* B2hi = (unsigned short*)region;
  unsigned short* B2lo = (unsigned short*)(region + 16384);
  float* h3p = (float*)region;                         // [64][64] swizzled
  unsigned short* B3hi = (unsigned short*)(region + 16384);
  unsigned short* B3lo = (unsigned short*)(region + 24576);

  const int tid = threadIdx.x;
  const int lane = tid & 63;          // lane == zone z for producer phases
  const int l15 = lane & 15;
  const int lhi = lane >> 4;
  const int w = __builtin_amdgcn_readfirstlane(tid >> 6);
  const int i = blockIdx.x;

  const float t = times[i];

  // recover LN0 scalars from the st-free closed form (alpha, gma are cheap)
  // scal folded: mean/E2 of input LN use Sum(pa), Sum(pa^2) which are baked in
  // via c_pa? No: they come from scal — but alpha/gma only need t and two
  // scalars; pass them via st? Simpler: recompute from first two st slots?
  // We keep the original scal-based computation: scal was merged into st[384..]
  const float m0 = (st[384] + t + 1.0f) * (1.0f / 97.0f);
  const float e2 = (st[385] + t * t + 1.0f) * (1.0f / 97.0f);
  const float alpha = 1.0f / sqrtf(e2 - m0 * m0 + 1e-5f);
  const float gma = -m0 * alpha;

  const f32x4 zero4 = {0.f, 0.f, 0.f, 0.f};

  // ---- u(k) once per k + block sums; closed-form LN1 stats per z ----
  {
    int k = tid;
    float u = fmaf(t, w_t[k], c_pa[k]);
    u = fmaf(alpha, u, c_const[k]);
    u = fmaf(gma, c_g[k], u);
    u_lds[k] = u;
    float su = u, sq = u * u;
    #pragma unroll
    for (int off = 1; off < 64; off <<= 1) {
      su += __shfl_xor(su, off, 64);
      sq += __shfl_xor(sq, off, 64);
    }
    if (lane == 0) { ps1[w] = su; ps2[w] = sq; }
  }
  __syncthreads();
  float mu1, inv1;
  {
    float U1 = ps1[0] + ps1[1] + ps1[2] + ps1[3];
    float Qu = ps2[0] + ps2[1] + ps2[2] + ps2[3];
    float A1 = st[lane], Qz = st[64 + lane];
    float dpa = st[128 + lane], dwt = st[192 + lane];
    float dcg = st[256 + lane], dcc = st[320 + lane];
    float s1 = fmaf(alpha, A1, U1);
    float uwz = fmaf(alpha, fmaf(t, dwt, dpa), fmaf(gma, dcg, dcc));
    float s2 = Qu + 2.0f * alpha * uwz + alpha * alpha * Qz;
    mu1 = s1 * (1.0f / 256.0f);
    inv1 = 1.0f / sqrtf(s2 * (1.0f / 256.0f) - mu1 * mu1 + 1e-5f);
  }

  // ---- GEMM1: h2[128][64] = W2 @ h1, K=256 in 2 chunks of 128 ----
  f32x4 acc[2][4];
  #pragma unroll
  for (int a = 0; a < 2; ++a)
    #pragma unroll
    for (int b = 0; b < 4; ++b) acc[a][b] = zero4;

  for (int kc = 0; kc < 2; ++kc) {
    if (kc) __syncthreads();   // previous chunk's MFMA readers done
    // producers: h1 for k in [kc*128+32w, +32) at z = lane
    #pragma unroll
    for (int q = 0; q < 4; ++q) {
      int kb = kc * 128 + w * 32 + q * 8;
      f32x4 u0 = *(const f32x4*)(u_lds + kb);
      f32x4 u1 = *(const f32x4*)(u_lds + kb + 4);
      bf16x8 vh, vl;
      #pragma unroll
      for (int j = 0; j < 8; ++j) {
        int k = kb + j;
        float u = (j < 4) ? u0[j & 3] : u1[j & 3];
        float p = fmaf(alpha, wzT[k * 64 + lane], u);
        float x = (p - mu1) * inv1;
        float h = fmaxf(fmaf(g1[k], x, be1[k]), 0.f);
        unsigned short hb = f2b(h);
        vh[j] = (short)hb;
        vl[j] = (short)f2b(h - b2f(hb));
      }
      int slot = ((w * 4 + lhi) * 64 + q * 16 + l15) * 8;
      *(bf16x8*)(B1hi + slot) = vh;
      *(bf16x8*)(B1lo + slot) = vl;
    }
    __syncthreads();
    // MFMA: wave owns M rows [32w, 32w+32)
    for (int kt = 0; kt < 4; ++kt) {
      int ktg = kc * 4 + kt;
      bf16x8 a0h = *(const bf16x8*)(W2Ah + (((2 * w + 0) * 8 + ktg) * 64 + lane) * 8);
      bf16x8 a0l = *(const bf16x8*)(W2Al + (((2 * w + 0) * 8 + ktg) * 64 + lane) * 8);
      bf16x8 a1h = *(const bf16x8*)(W2Ah + (((2 * w + 1) * 8 + ktg) * 64 + lane) * 8);
      bf16x8 a1l = *(const bf16x8*)(W2Al + (((2 * w + 1) * 8 + ktg) * 64 + lane) * 8);
      #pragma unroll
      for (int nt = 0; nt < 4; ++nt) {
        bf16x8 bh = *(const bf16x8*)(B1hi + ((kt * 4 + nt) * 64 + lane) * 8);
        bf16x8 bl = *(const bf16x8*)(B1lo + ((kt * 4 + nt) * 64 + lane) * 8);
        acc[0][nt] = MFMA(a0h, bh, acc[0][nt]);
        acc[0][nt] = MFMA(a0h, bl, acc[0][nt]);
        acc[0][nt] = MFMA(a0l, bh, acc[0][nt]);
        acc[1][nt] = MFMA(a1h, bh, acc[1][nt]);
        acc[1][nt] = MFMA(a1h, bl, acc[1][nt]);
        acc[1][nt] = MFMA(a1l, bh, acc[1][nt]);
      }
    }
  }
  // +b2, LN2 stats (over 128 rows, per column)
  #pragma unroll
  for (int mti = 0; mti < 2; ++mti) {
    f32x4 bv = *(const f32x4*)(b2 + w * 32 + mti * 16 + lhi * 4);
    #pragma unroll
    for (int nt = 0; nt < 4; ++nt) acc[mti][nt] += bv;
  }
  {
    float sa[4], sb[4];
    #pragma unroll
    for (int nt = 0; nt < 4; ++nt) {
      float x1 = 0.f, x2 = 0.f;
      #pragma unroll
      for (int mti = 0; mti < 2; ++mti)
        #pragma unroll
        for (int r = 0; r < 4; ++r) { float v = acc[mti][nt][r]; x1 += v; x2 += v * v; }
      x1 += __shfl_xor(x1, 16, 64); x1 += __shfl_xor(x1, 32, 64);
      x2 += __shfl_xor(x2, 16, 64); x2 += __shfl_xor(x2, 32, 64);
      sa[nt] = x1; sb[nt] = x2;
    }
    if (lane < 16) {
      #pragma unroll
      for (int nt = 0; nt < 4; ++nt) {
        ps1[w * 64 + nt * 16 + lane] = sa[nt];
        ps2[w * 64 + nt * 16 + lane] = sb[nt];
      }
    }
  }
  __syncthreads();            // all MFMAs done: region reusable, ps visible
  #pragma unroll
  for (int mti = 0; mti < 2; ++mti)
    #pragma unroll
    for (int nt = 0; nt < 4; ++nt)
      #pragma unroll
      for (int r = 0; r < 4; ++r) {
        int row = w * 32 + mti * 16 + lhi * 4 + r;
        h2p[row * 64 + SWZ(row, nt * 16 + l15)] = acc[mti][nt][r];
      }
  __syncthreads();

  // ---- B2 producers: read own rows into regs FIRST (region gets overwritten) ----
  float mu2, inv2;
  {
    float a = ps1[lane] + ps1[64 + lane] + ps1[128 + lane] + ps1[192 + lane];
    float b = ps2[lane] + ps2[64 + lane] + ps2[128 + lane] + ps2[192 + lane];
    mu2 = a * (1.0f / 128.0f);
    inv2 = 1.0f / sqrtf(b * (1.0f / 128.0f) - mu2 * mu2 + 1e-5f);
  }
  float hv[32];
  #pragma unroll
  for (int mi = 0; mi < 32; ++mi) {
    int row = w * 32 + mi;
    hv[mi] = h2p[row * 64 + SWZ(row, lane)];
  }
  __syncthreads();            // all h2p reads done before B2 frag writes
  #pragma unroll
  for (int q = 0; q < 4; ++q) {
    bf16x8 vh, vl;
    #pragma unroll
    for (int j = 0; j < 8; ++j) {
      int mi = q * 8 + j;
      int mm = w * 32 + mi;
      float x = (hv[mi] - mu2) * inv2;
      float h = fmaxf(fmaf(g2[mm], x, be2[mm]), 0.f);
      unsigned short hb = f2b(h);
      vh[j] = (short)hb;
      vl[j] = (short)f2b(h - b2f(hb));
    }
    int slot = ((w * 4 + lhi) * 64 + q * 16 + l15) * 8;
    *(bf16x8*)(B2hi + slot) = vh;
    *(bf16x8*)(B2lo + slot) = vl;
  }
  __syncthreads();

  // ---- GEMM2: h3[64][64] = W3 @ h2, wave owns rows [16w, 16w+16) ----
  f32x4 acc2[4];
  #pragma unroll
  for (int b = 0; b < 4; ++b) acc2[b] = zero4;
  for (int kt = 0; kt < 4; ++kt) {
    bf16x8 ah = *(const bf16x8*)(W3Ah + ((w * 4 + kt) * 64 + lane) * 8);
    bf16x8 al = *(const bf16x8*)(W3Al + ((w * 4 + kt) * 64 + lane) * 8);
    #pragma unroll
    for (int nt = 0; nt < 4; ++nt) {
      bf16x8 bh = *(const bf16x8*)(B2hi + ((kt * 4 + nt) * 64 + lane) * 8);
      bf16x8 bl = *(const bf16x8*)(B2lo + ((kt * 4 + nt) * 64 + lane) * 8);
      acc2[nt] = MFMA(ah, bh, acc2[nt]);
      acc2[nt] = MFMA(ah, bl, acc2[nt]);
      acc2[nt] = MFMA(al, bh, acc2[nt]);
    }
  }
  {
    f32x4 bv = *(const f32x4*)(b3 + w * 16 + lhi * 4);
    #pragma unroll
    for (int nt = 0; nt < 4; ++nt) acc2[nt] += bv;
  }
  {
    float sa[4], sb[4];
    #pragma unroll
    for (int nt = 0; nt < 4; ++nt) {
      float x1 = 0.f, x2 = 0.f;
      #pragma unroll
      for (int r = 0; r < 4; ++r) { float v = acc2[nt][r]; x1 += v; x2 += v * v; }
      x1 += __shfl_xor(x1, 16, 64); x1 += __shfl_xor(x1, 32, 64);
      x2 += __shfl_xor(x2, 16, 64); x2 += __shfl_xor(x2, 32, 64);
      sa[nt] = x1; sb[nt] = x2;
    }
    if (lane < 16) {
      #pragma unroll
      for (int nt = 0; nt < 4; ++nt) {
        ps1[w * 64 + nt * 16 + lane] = sa[nt];
        ps2[w * 64 + nt * 16 + lane] = sb[nt];
      }
    }
  }
  __syncthreads();            // B2 frags free, ps visible
  #pragma unroll
  for (int nt = 0; nt < 4; ++nt)
    #pragma unroll
    for (int r = 0; r < 4; ++r) {
      int row = w * 16 + lhi * 4 + r;
      h3p[row * 64 + SWZ(row, nt * 16 + l15)] = acc2[nt][r];
    }
  __syncthreads();

  // ---- B3 producers: h3p lives in [0,16K), B3 frags in [16K,32K) — no overlap ----
  float mu3, inv3;
  {
    float a = ps1[lane] + ps1[64 + lane] + ps1[128 + lane] + ps1[192 + lane];
    float b = ps2[lane] + ps2[64 + lane] + ps2[128 + lane] + ps2[192 + lane];
    mu3 = a * (1.0f / 64.0f);
    inv3 = 1.0f / sqrtf(b * (1.0f / 64.0f) - mu3 * mu3 + 1e-5f);
  }
  #pragma unroll
  for (int q = 0; q < 2; ++q) {
    int o = w * 2 + q;        // octet 0..7
    bf16x8 vh, vl;
    #pragma unroll
    for (int j = 0; j < 8; ++j) {
      int mm = o * 8 + j;
      float v = h3p[mm * 64 + SWZ(mm, lane)];
      float x = (v - mu3) * inv3;
      float h = fmaxf(fmaf(g3[mm], x, be3[mm]), 0.f);
      unsigned short hb = f2b(h);
      vh[j] = (short)hb;
      vl[j] = (short)f2b(h - b2f(hb));
    }
    int slot = (((o >> 2) * 4 + lhi) * 64 + (o & 3) * 16 + l15) * 8;
    *(bf16x8*)(B3hi + slot) = vh;
    *(bf16x8*)(B3lo + slot) = vl;
  }
  __syncthreads();

  // ---- GEMM3: raw[64][64] = W4 @ h3, wave owns outputs [16w, 16w+16) ----
  f32x4 acc3[4];
  #pragma unroll
  for (int b = 0; b < 4; ++b) acc3[b] = zero4;
  for (int kt = 0; kt < 2; ++kt) {
    bf16x8 ah = *(const bf16x8*)(W4Ah + ((w * 2 + kt) * 64 + lane) * 8);
    bf16x8 al = *(const bf16x8*)(W4Al + ((w * 2 + kt) * 64 + lane) * 8);
    #pragma unroll
    for (int nt = 0; nt < 4; ++nt) {
      bf16x8 bh = *(const bf16x8*)(B3hi + ((kt * 4 + nt) * 64 + lane) * 8);
      bf16x8 bl = *(const bf16x8*)(B3lo + ((kt * 4 + nt) * 64 + lane) * 8);
      acc3[nt] = MFMA(ah, bh, acc3[nt]);
      acc3[nt] = MFMA(ah, bl, acc3[nt]);
      acc3[nt] = MFMA(al, bh, acc3[nt]);
    }
  }
  // epilogue: +b4, mask by adjacency, argmax keys
  f32x4 b4v = *(const f32x4*)(b4 + w * 16 + lhi * 4);
  unsigned long long kbest[4];
  #pragma unroll
  for (int nt = 0; nt < 4; ++nt) {
    unsigned long long am = adj[nt * 16 + l15];
    unsigned long long kb = 0ull;
    #pragma unroll
    for (int r = 0; r < 4; ++r) {
      int o = w * 16 + lhi * 4 + r;
      float raw = acc3[nt][r] + b4v[r];
      float val = ((am >> o) & 1ull) ? raw : -__builtin_huge_valf();
      unsigned u = __float_as_uint(val);
      u = (u & 0x80000000u) ? ~u : (u | 0x80000000u);   // order-preserving map
      unsigned long long key = ((unsigned long long)u << 6) | (unsigned long long)(63 - o);
      if (key > kb) kb = key;                            // ties -> lowest o
    }
    unsigned long long oth = __shfl_xor(kb, 16, 64); if (oth > kb) kb = oth;
    oth = __shfl_xor(kb, 32, 64); if (oth > kb) kb = oth;
    kbest[nt] = kb;
  }
  if (lane < 16) {
    #pragma unroll
    for (int nt = 0; nt < 4; ++nt) pk[w * 64 + nt * 16 + lane] = kbest[nt];
  }
  __syncthreads();
  if (tid < 64) {
    unsigned long long k0 = pk[tid], k1 = pk[64 + tid];
    unsigned long long k2 = pk[128 + tid], k3 = pk[192 + tid];
    unsigned long long a = k0 > k1 ? k0 : k1;
    unsigned long long b = k2 > k3 ? k2 : k3;
    unsigned long long bb = a > b ? a : b;
    nxt[(size_t)i * 64 + tid] = (unsigned char)(63u - (unsigned)(bb & 63ull));
  }
}

// small helper: append scal (sum pa, sum pa^2) into st[384..385]
__global__ void k_scal2st(const float* __restrict__ scal, float* __restrict__ st) {
  if (threadIdx.x < 2) st[384 + threadIdx.x] = scal[threadIdx.x];
}

// ---------------- trajectory via parallel map-composition scan ----------------

__global__ void k_scan_a(const unsigned char* __restrict__ nxt,
                         unsigned char* __restrict__ cmap) {
  int c = blockIdx.x, lane = threadIdx.x;  // 64 threads
  int g = lane;                            // identity map
  const unsigned char* p = nxt + (size_t)c * 128 * 64;
  for (int s = 0; s < 128; ++s) {
    int sig = p[s * 64 + lane];
    g = __shfl(sig, g, 64);
  }
  cmap[c * 64 + lane] = (unsigned char)g;
}

__global__ void k_scan_b(const unsigned char* __restrict__ cmap,
                         int* __restrict__ startz) {
  int lane = threadIdx.x;
  int cur = 0;
  for (int c = 0; c < 256; ++c) {
    if (lane == 0) startz[c] = cur;
    int row = cmap[c * 64 + lane];
    cur = __shfl(row, cur, 64);
  }
}

__global__ void k_scan_c(const unsigned char* __restrict__ nxt,
                         const int* __restrict__ startz,
                         unsigned char* __restrict__ zones) {
  int c = blockIdx.x, lane = threadIdx.x;
  int cur = startz[c];
  const unsigned char* p = nxt + (size_t)c * 128 * 64;
  for (int s = 0; s < 128; ++s) {
    if (lane == 0) zones[c * 128 + s] = (unsigned char)cur;
    int row = p[s * 64 + lane];
    cur = __shfl(row, cur, 64);
  }
}

// ---------------- pass 3: logits for the actual zone at each step ----------------

__global__ void k_pass3(
    const float* __restrict__ times, const unsigned char* __restrict__ zones,
    const float* __restrict__ c_pa, const float* __restrict__ w_t,
    const float* __restrict__ c_g, const float* __restrict__ c_const,
    const float* __restrict__ scal, const float* __restrict__ wzZ,
    const float* __restrict__ W2T, const float* __restrict__ W3T,
    const float* __restrict__ W4T,
    const float* __restrict__ b2, const float* __restrict__ b3,
    const float* __restrict__ b4,
    const float* __restrict__ g1, const float* __restrict__ be1,
    const float* __restrict__ g2, const float* __restrict__ be2,
    const float* __restrict__ g3, const float* __restrict__ be3,
    const unsigned long long* __restrict__ adj,
    float* __restrict__ out) {
  __shared__ float h1s[4][256];
  __shared__ float h2s[4][128];
  __shared__ float h3s[4][64];
  const int tid = threadIdx.x, lane = tid & 63, w = tid >> 6;
  const int i = blockIdx.x * 4 + w;            // one timestep per wave
  const int z = zones[i];
  const float t = times[i];
  const float m  = (scal[0] + t + 1.0f) * (1.0f / 97.0f);
  const float e2 = (scal[1] + t * t + 1.0f) * (1.0f / 97.0f);
  const float alpha = 1.0f / sqrtf(e2 - m * m + 1e-5f);
  const float gma = -m * alpha;

  float pre[4], s1 = 0.f, s2 = 0.f;
  #pragma unroll
  for (int q = 0; q < 4; ++q) {
    int k = lane + q * 64;
    float p = alpha * (c_pa[k] + t * w_t[k]) + gma * c_g[k] + c_const[k]
            + alpha * wzZ[z * 256 + k];
    pre[q] = p; s1 += p; s2 += p * p;
  }
  #pragma unroll
  for (int off = 32; off; off >>= 1) {
    s1 += __shfl_xor(s1, off, 64); s2 += __shfl_xor(s2, off, 64);
  }
  float mu = s1 * (1.0f / 256.0f);
  float inv = 1.0f / sqrtf(s2 * (1.0f / 256.0f) - mu * mu + 1e-5f);
  #pragma unroll
  for (int q = 0; q < 4; ++q) {
    int k = lane + q * 64;
    h1s[w][k] = fmaxf(g1[k] * ((pre[q] - mu) * inv) + be1[k], 0.f);
  }
  __syncthreads();

  float a0 = 0.f, a1 = 0.f;
  for (int k = 0; k < 256; ++k) {
    float hv = h1s[w][k];
    a0 = fmaf(W2T[k * 128 + lane], hv, a0);
    a1 = fmaf(W2T[k * 128 + 64 + lane], hv, a1);
  }
  a0 += b2[lane]; a1 += b2[64 + lane];
  s1 = a0 + a1; s2 = a0 * a0 + a1 * a1;
  #pragma unroll
  for (int off = 32; off; off >>= 1) {
    s1 += __shfl_xor(s1, off, 64); s2 += __shfl_xor(s2, off, 64);
  }
  mu = s1 * (1.0f / 128.0f);
  inv = 1.0f / sqrtf(s2 * (1.0f / 128.0f) - mu * mu + 1e-5f);
  h2s[w][lane]      = fmaxf(g2[lane] * ((a0 - mu) * inv) + be2[lane], 0.f);
  h2s[w][64 + lane] = fmaxf(g2[64 + lane] * ((a1 - mu) * inv) + be2[64 + lane], 0.f);
  __syncthreads();

  float a3 = 0.f;
  for (int k = 0; k < 128; ++k) a3 = fmaf(W3T[k * 64 + lane], h2s[w][k], a3);
  a3 += b3[lane];
  s1 = a3; s2 = a3 * a3;
  #pragma unroll
  for (int off = 32; off; off >>= 1) {
    s1 += __shfl_xor(s1, off, 64); s2 += __shfl_xor(s2, off, 64);
  }
  mu = s1 * (1.0f / 64.0f);
  inv = 1.0f / sqrtf(s2 * (1.0f / 64.0f) - mu * mu + 1e-5f);
  h3s[w][lane] = fmaxf(g3[lane] * ((a3 - mu) * inv) + be3[lane], 0.f);
  __syncthreads();

  float a4 = 0.f;
  for (int k = 0; k < 64; ++k) a4 = fmaf(W4T[k * 64 + lane], h3s[w][k], a4);
  a4 += b4[lane];
  unsigned long long amask = adj[z];
  float predv = ((amask >> lane) & 1ull) ? a4 : -50.0f;
  out[(size_t)i * 64 + lane] = predv;
}

// ---------------- launch ----------------

extern "C" void kernel_launch(void* const* d_in, const int* in_sizes, int n_in,
                              void* d_out, int out_size, void* d_ws, size_t ws_size,
                              hipStream_t stream) {
  const float* pa    = (const float*)d_in[0];
  const float* times = (const float*)d_in[1];
  const int*   ei    = (const int*)d_in[3];
  const float* g0    = (const float*)d_in[4];
  const float* b0    = (const float*)d_in[5];
  const float* W1    = (const float*)d_in[6];
  const float* b1    = (const float*)d_in[7];
  const float* g1    = (const float*)d_in[8];
  const float* be1   = (const float*)d_in[9];
  const float* W2    = (const float*)d_in[10];
  const float* b2    = (const float*)d_in[11];
  const float* g2    = (const float*)d_in[12];
  const float* be2   = (const float*)d_in[13];
  const float* W3    = (const float*)d_in[14];
  const float* b3    = (const float*)d_in[15];
  const float* g3    = (const float*)d_in[16];
  const float* be3   = (const float*)d_in[17];
  const float* W4    = (const float*)d_in[18];
  const float* b4    = (const float*)d_in[19];

  char* ws = (char*)d_ws;
  float* c_pa    = (float*)(ws + 0);
  float* w_t     = (float*)(ws + 1024);
  float* c_g     = (float*)(ws + 2048);
  float* c_const = (float*)(ws + 3072);
  float* scal    = (float*)(ws + 4096);
  unsigned long long* adj = (unsigned long long*)(ws + 4608);
  float* wzT = (float*)(ws + 5120);                   // 64 KB
  float* wzZ = (float*)(ws + 70656);                  // 64 KB
  float* W2T = (float*)(ws + 136192);                 // 128 KB
  float* W3T = (float*)(ws + 267264);                 // 32 KB
  float* W4T = (float*)(ws + 300032);                 // 16 KB
  unsigned short* W2Ah = (unsigned short*)(ws + 316416);  // 64 KB
  unsigned short* W2Al = (unsigned short*)(ws + 381952);  // 64 KB
  unsigned short* W3Ah = (unsigned short*)(ws + 447488);  // 16 KB
  unsigned short* W3Al = (unsigned short*)(ws + 463872);  // 16 KB
  unsigned short* W4Ah = (unsigned short*)(ws + 480256);  // 8 KB
  unsigned short* W4Al = (unsigned short*)(ws + 488448);  // 8 KB
  float* st = (float*)(ws + 496640);                      // 1.5 KB + 2 scal
  unsigned char* nxt  = (unsigned char*)(ws + 498688);    // 2 MB
  unsigned char* cmap = (unsigned char*)(ws + 2595840);   // 16 KB
  int* startz = (int*)(ws + 2612224);                     // 1 KB
  unsigned char* zones = (unsigned char*)(ws + 2613248);  // 32 KB

  k_prep<<<1, 256, 0, stream>>>(pa, g0, b0, W1, b1, c_pa, w_t, c_g, c_const,
                                scal, wzT, wzZ);
  k_prep2<<<1, 64, 0, stream>>>(c_pa, w_t, c_g, c_const, wzT, st);
  k_scal2st<<<1, 64, 0, stream>>>(scal, st);
  k_adj<<<1, 256, 0, stream>>>(ei, adj);
  k_tr<<<176, 256, 0, stream>>>(W2, W3, W4, W2T, W3T, W4T);
  k_wsplit<<<176, 256, 0, stream>>>(W2, W3, W4, W2Ah, W2Al, W3Ah, W3Al, W4Ah, W4Al);
  k_pass1<<<32768, 256, 0, stream>>>(times, c_pa, w_t, c_g, c_const, wzT, st,
                                     W2Ah, W2Al, W3Ah, W3Al, W4Ah, W4Al,
                                     b2, b3, b4, g1, be1, g2, be2, g3, be3,
                                     adj, nxt);
  k_scan_a<<<256, 64, 0, stream>>>(nxt, cmap);
  k_scan_b<<<1, 64, 0, stream>>>(cmap, startz);
  k_scan_c<<<256, 64, 0, stream>>>(nxt, startz, zones);
  k_pass3<<<8192, 256, 0, stream>>>(times, zones, c_pa, w_t, c_g, c_const, scal,
                                    wzZ, W2T, W3T, W4T, b2, b3, b4,
                                    g1, be1, g2, be2, g3, be3, adj, (float*)d_out);
}

// Round 5
// 809.243 us; speedup vs baseline: 4.2832x; 1.2739x over previous
//
#include <hip/hip_runtime.h>
#include <stdint.h>

typedef __attribute__((ext_vector_type(8))) short bf16x8;
typedef __attribute__((ext_vector_type(4))) float f32x4;
typedef __attribute__((ext_vector_type(4))) unsigned int u32x4;

#define MFMA(a, b, c) __builtin_amdgcn_mfma_f32_16x16x32_bf16(a, b, c, 0, 0, 0)

__device__ __forceinline__ unsigned short f2b(float x) {
  unsigned u = __float_as_uint(x);
  return (unsigned short)((u + 0x7fffu + ((u >> 16) & 1u)) >> 16);
}
__device__ __forceinline__ float b2f(unsigned short h) {
  return __uint_as_float(((unsigned)h) << 16);
}

// truncation-based Dekker split of two fp32 into packed bf16 hi/lo dwords.
// hi = trunc-to-bf16(h) (exact residual r = h - hi in fp32), lo = trunc(r).
// total error <= 2^-16 * |h|  — ~4 VALU ops/element vs ~12 for RNE path.
struct u2 { unsigned hi, lo; };
__device__ __forceinline__ u2 split2(float h0, float h1) {
  unsigned u0 = __float_as_uint(h0), u1 = __float_as_uint(h1);
  u2 r;
  r.hi = (u0 >> 16) | (u1 & 0xffff0000u);
  float r0 = h0 - __uint_as_float(u0 & 0xffff0000u);
  float r1 = h1 - __uint_as_float(u1 & 0xffff0000u);
  r.lo = (__float_as_uint(r0) >> 16) | (__float_as_uint(r1) & 0xffff0000u);
  return r;
}

// scratch swizzle: identical on write and read, keyed on row bits
#define SWZ(row, col) ((col) ^ ((((row) >> 2) & 1) << 4) ^ ((((row) >> 3) & 1) << 2))

// ---------------- setup kernels ----------------

__global__ void k_prep(const float* __restrict__ pa, const float* __restrict__ g0,
                       const float* __restrict__ b0, const float* __restrict__ W1,
                       const float* __restrict__ b1,
                       float* __restrict__ c_pa, float* __restrict__ w_t,
                       float* __restrict__ c_g, float* __restrict__ c_const,
                       float* __restrict__ scal, float* __restrict__ wzT,
                       float* __restrict__ wzZ) {
  int j = threadIdx.x;  // 256 threads, one per W1 row
  const float* wr = W1 + j * 97;
  float cg = 0.f, cc = 0.f, cp = 0.f;
  for (int k = 0; k < 97; ++k) { float w = wr[k]; cg += w * g0[k]; cc += w * b0[k]; }
  for (int k = 0; k < 32; ++k) cp += wr[k] * g0[k] * pa[k];
  c_g[j] = cg;
  c_const[j] = cc + b1[j];
  c_pa[j] = cp;
  w_t[j] = wr[32] * g0[32];
  for (int z = 0; z < 64; ++z) {
    float v = wr[33 + z] * g0[33 + z];
    wzT[j * 64 + z] = v;     // [k][z]
    wzZ[z * 256 + j] = v;    // [z][k]
  }
  if (j == 0) {
    float s = 0.f, q = 0.f;
    for (int k = 0; k < 32; ++k) { float x = pa[k]; s += x; q += x * x; }
    scal[0] = s; scal[1] = q;
  }
}

// st[0..383]: per-z tables (A1, Qz, dpa, dwt, dcg, dcc)
// st[384..385]: scal (filled by k_scal2st)
// st[386..399]: SP SW SG SC | PP PW PG PC WW WG WC GG GC CC (Gram of u-coef vecs)
__global__ void k_prep2(const float* __restrict__ c_pa, const float* __restrict__ w_t,
                        const float* __restrict__ c_g, const float* __restrict__ c_const,
                        const float* __restrict__ wzT, float* __restrict__ st) {
  int tid = threadIdx.x;  // 128
  if (tid < 64) {
    int z = tid;
    float A = 0.f, Q = 0.f, dpa = 0.f, dwt = 0.f, dcg = 0.f, dcc = 0.f;
    for (int k = 0; k < 256; ++k) {
      float wz = wzT[k * 64 + z];
      A += wz; Q = fmaf(wz, wz, Q);
      dpa = fmaf(c_pa[k], wz, dpa);
      dwt = fmaf(w_t[k], wz, dwt);
      dcg = fmaf(c_g[k], wz, dcg);
      dcc = fmaf(c_const[k], wz, dcc);
    }
    st[z] = A; st[64 + z] = Q; st[128 + z] = dpa;
    st[192 + z] = dwt; st[256 + z] = dcg; st[320 + z] = dcc;
  } else {
    int lane = tid - 64;  // wave 1
    float acc[14];
    #pragma unroll
    for (int m = 0; m < 14; ++m) acc[m] = 0.f;
    for (int k = lane; k < 256; k += 64) {
      float P = c_pa[k], W = w_t[k], G = c_g[k], C = c_const[k];
      acc[0] += P; acc[1] += W; acc[2] += G; acc[3] += C;
      acc[4] = fmaf(P, P, acc[4]); acc[5] = fmaf(P, W, acc[5]);
      acc[6] = fmaf(P, G, acc[6]); acc[7] = fmaf(P, C, acc[7]);
      acc[8] = fmaf(W, W, acc[8]); acc[9] = fmaf(W, G, acc[9]);
      acc[10] = fmaf(W, C, acc[10]); acc[11] = fmaf(G, G, acc[11]);
      acc[12] = fmaf(G, C, acc[12]); acc[13] = fmaf(C, C, acc[13]);
    }
    #pragma unroll
    for (int off = 1; off < 64; off <<= 1) {
      #pragma unroll
      for (int m = 0; m < 14; ++m) acc[m] += __shfl_xor(acc[m], off, 64);
    }
    if (lane == 0) {
      #pragma unroll
      for (int m = 0; m < 14; ++m) st[386 + m] = acc[m];
    }
  }
}

__global__ void k_scal2st(const float* __restrict__ scal, float* __restrict__ st) {
  if (threadIdx.x < 2) st[384 + threadIdx.x] = scal[threadIdx.x];
}

__global__ void k_adj(const int* __restrict__ ei, unsigned long long* __restrict__ adj) {
  int t = threadIdx.x;  // 256
  if (t < 64) adj[t] = 1ull << t;
  __syncthreads();
  int u = ei[t] & 63, v = ei[256 + t] & 63;
  atomicOr(&adj[u], 1ull << v);
  atomicOr(&adj[v], 1ull << u);
}

// Pre-split weights into MFMA A-fragment order, bf16 hi/lo (RNE, done once).
// A-frag (16x16x32): elem j of lane l = A[mt*16 + (l&15)][kt*32 + (l>>4)*8 + j]
__global__ void k_wsplit(const float* __restrict__ W2, const float* __restrict__ W3,
                         const float* __restrict__ W4,
                         unsigned short* __restrict__ W2Ah, unsigned short* __restrict__ W2Al,
                         unsigned short* __restrict__ W3Ah, unsigned short* __restrict__ W3Al,
                         unsigned short* __restrict__ W4Ah, unsigned short* __restrict__ W4Al) {
  int idx = blockIdx.x * 256 + threadIdx.x;
  float w; unsigned short* ph; unsigned short* pl; int o;
  if (idx < 32768) {                       // W2 [128][256]
    int mt = idx >> 12, kt = (idx >> 9) & 7, lane = (idx >> 3) & 63, j = idx & 7;
    int m = mt * 16 + (lane & 15), k = kt * 32 + (lane >> 4) * 8 + j;
    w = W2[m * 256 + k]; ph = W2Ah; pl = W2Al; o = idx;
  } else if (idx < 40960) {                // W3 [64][128]
    int r = idx - 32768;
    int mt = r >> 11, kt = (r >> 9) & 3, lane = (r >> 3) & 63, j = r & 7;
    int m = mt * 16 + (lane & 15), k = kt * 32 + (lane >> 4) * 8 + j;
    w = W3[m * 128 + k]; ph = W3Ah; pl = W3Al; o = r;
  } else if (idx < 45056) {                // W4 [64][64]
    int r = idx - 40960;
    int mt = r >> 10, kt = (r >> 9) & 1, lane = (r >> 3) & 63, j = r & 7;
    int m = mt * 16 + (lane & 15), k = kt * 32 + (lane >> 4) * 8 + j;
    w = W4[m * 64 + k]; ph = W4Ah; pl = W4Al; o = r;
  } else return;
  unsigned short hb = f2b(w);
  ph[o] = hb;
  pl[o] = f2b(w - b2f(hb));
}

// ---------------- pass 1: transition table next[i][z], MFMA split-bf16 ----------------

__global__ __launch_bounds__(256, 4) void k_pass1(
    const float* __restrict__ times,
    const float* __restrict__ c_pa, const float* __restrict__ w_t,
    const float* __restrict__ c_g, const float* __restrict__ c_const,
    const float* __restrict__ wzT, const float* __restrict__ st,
    const unsigned short* __restrict__ W2Ah, const unsigned short* __restrict__ W2Al,
    const unsigned short* __restrict__ W3Ah, const unsigned short* __restrict__ W3Al,
    const unsigned short* __restrict__ W4Ah, const unsigned short* __restrict__ W4Al,
    const float* __restrict__ b2, const float* __restrict__ b3,
    const float* __restrict__ b4,
    const float* __restrict__ g1, const float* __restrict__ be1,
    const float* __restrict__ g2, const float* __restrict__ be2,
    const float* __restrict__ g3, const float* __restrict__ be3,
    const unsigned long long* __restrict__ adj,
    unsigned char* __restrict__ nxt) {
  __shared__ __align__(16) char region[32768];
  __shared__ float u_lds[256];
  __shared__ float ps1[256], ps2[256];
  __shared__ unsigned long long pk[256];

  unsigned short* B1hi = (unsigned short*)region;
  unsigned short* B1lo = (unsigned short*)(region + 16384);
  float* h2p = (float*)region;                         // [128][64] swizzled
  unsigned short* B2hi = (unsigned short*)region;
  unsigned short* B2lo = (unsigned short*)(region + 16384);
  float* h3p = (float*)region;                         // [64][64] swizzled
  unsigned short* B3hi = (unsigned short*)(region + 16384);
  unsigned short* B3lo = (unsigned short*)(region + 24576);

  const int tid = threadIdx.x;
  const int lane = tid & 63;          // lane == zone z for producer phases
  const int l15 = lane & 15;
  const int lhi = lane >> 4;
  const int w = __builtin_amdgcn_readfirstlane(tid >> 6);
  const int i = blockIdx.x;

  const float t = times[i];
  const float m0 = (st[384] + t + 1.0f) * (1.0f / 97.0f);
  const float e2 = (st[385] + t * t + 1.0f) * (1.0f / 97.0f);
  const float alpha = 1.0f / sqrtf(e2 - m0 * m0 + 1e-5f);
  const float gma = -m0 * alpha;

  const f32x4 zero4 = {0.f, 0.f, 0.f, 0.f};

  // ---- u(k) once per k + block sums; closed-form LN1 stats per z ----
  {
    int k = tid;
    float u = fmaf(t, w_t[k], c_pa[k]);
    u = fmaf(alpha, u, c_const[k]);
    u = fmaf(gma, c_g[k], u);
    u_lds[k] = u;
    float su = u, sq = u * u;
    #pragma unroll
    for (int off = 1; off < 64; off <<= 1) {
      su += __shfl_xor(su, off, 64);
      sq += __shfl_xor(sq, off, 64);
    }
    if (lane == 0) { ps1[w] = su; ps2[w] = sq; }
  }
  __syncthreads();
  float mu1, inv1;
  {
    float U1 = ps1[0] + ps1[1] + ps1[2] + ps1[3];
    float Qu = ps2[0] + ps2[1] + ps2[2] + ps2[3];
    float A1 = st[lane], Qz = st[64 + lane];
    float dpa = st[128 + lane], dwt = st[192 + lane];
    float dcg = st[256 + lane], dcc = st[320 + lane];
    float s1 = fmaf(alpha, A1, U1);
    float uwz = fmaf(alpha, fmaf(t, dwt, dpa), fmaf(gma, dcg, dcc));
    float s2 = Qu + 2.0f * alpha * uwz + alpha * alpha * Qz;
    mu1 = s1 * (1.0f / 256.0f);
    inv1 = 1.0f / sqrtf(s2 * (1.0f / 256.0f) - mu1 * mu1 + 1e-5f);
  }

  // ---- GEMM1: h2[128][64] = W2 @ h1, K=256 in 2 chunks of 128 ----
  f32x4 acc[2][4];
  #pragma unroll
  for (int a = 0; a < 2; ++a)
    #pragma unroll
    for (int b = 0; b < 4; ++b) acc[a][b] = zero4;

  for (int kc = 0; kc < 2; ++kc) {
    if (kc) __syncthreads();
    #pragma unroll
    for (int q = 0; q < 4; ++q) {
      int kb = kc * 128 + w * 32 + q * 8;
      f32x4 u0 = *(const f32x4*)(u_lds + kb);
      f32x4 u1 = *(const f32x4*)(u_lds + kb + 4);
      float hbuf[8];
      #pragma unroll
      for (int j = 0; j < 8; ++j) {
        int k = kb + j;
        float u = (j < 4) ? u0[j] : u1[j - 4];
        float p = fmaf(alpha, wzT[k * 64 + lane], u);
        float gi = g1[k] * inv1;
        float bb = fmaf(-mu1, gi, be1[k]);
        hbuf[j] = fmaxf(fmaf(p, gi, bb), 0.f);
      }
      u32x4 vh, vl;
      #pragma unroll
      for (int e = 0; e < 4; ++e) {
        u2 s = split2(hbuf[2 * e], hbuf[2 * e + 1]);
        vh[e] = s.hi; vl[e] = s.lo;
      }
      int slotd = ((w * 4 + lhi) * 64 + q * 16 + l15) * 4;
      *(u32x4*)((unsigned*)B1hi + slotd) = vh;
      *(u32x4*)((unsigned*)B1lo + slotd) = vl;
    }
    __syncthreads();
    for (int kt = 0; kt < 4; ++kt) {
      int ktg = kc * 4 + kt;
      bf16x8 a0h = *(const bf16x8*)(W2Ah + (((2 * w + 0) * 8 + ktg) * 64 + lane) * 8);
      bf16x8 a0l = *(const bf16x8*)(W2Al + (((2 * w + 0) * 8 + ktg) * 64 + lane) * 8);
      bf16x8 a1h = *(const bf16x8*)(W2Ah + (((2 * w + 1) * 8 + ktg) * 64 + lane) * 8);
      bf16x8 a1l = *(const bf16x8*)(W2Al + (((2 * w + 1) * 8 + ktg) * 64 + lane) * 8);
      #pragma unroll
      for (int nt = 0; nt < 4; ++nt) {
        bf16x8 bh = *(const bf16x8*)(B1hi + ((kt * 4 + nt) * 64 + lane) * 8);
        bf16x8 bl = *(const bf16x8*)(B1lo + ((kt * 4 + nt) * 64 + lane) * 8);
        acc[0][nt] = MFMA(a0h, bh, acc[0][nt]);
        acc[0][nt] = MFMA(a0h, bl, acc[0][nt]);
        acc[0][nt] = MFMA(a0l, bh, acc[0][nt]);
        acc[1][nt] = MFMA(a1h, bh, acc[1][nt]);
        acc[1][nt] = MFMA(a1h, bl, acc[1][nt]);
        acc[1][nt] = MFMA(a1l, bh, acc[1][nt]);
      }
    }
  }
  #pragma unroll
  for (int mti = 0; mti < 2; ++mti) {
    f32x4 bv = *(const f32x4*)(b2 + w * 32 + mti * 16 + lhi * 4);
    #pragma unroll
    for (int nt = 0; nt < 4; ++nt) acc[mti][nt] += bv;
  }
  {
    float sa[4], sb[4];
    #pragma unroll
    for (int nt = 0; nt < 4; ++nt) {
      float x1 = 0.f, x2 = 0.f;
      #pragma unroll
      for (int mti = 0; mti < 2; ++mti)
        #pragma unroll
        for (int r = 0; r < 4; ++r) { float v = acc[mti][nt][r]; x1 += v; x2 += v * v; }
      x1 += __shfl_xor(x1, 16, 64); x1 += __shfl_xor(x1, 32, 64);
      x2 += __shfl_xor(x2, 16, 64); x2 += __shfl_xor(x2, 32, 64);
      sa[nt] = x1; sb[nt] = x2;
    }
    if (lane < 16) {
      #pragma unroll
      for (int nt = 0; nt < 4; ++nt) {
        ps1[w * 64 + nt * 16 + lane] = sa[nt];
        ps2[w * 64 + nt * 16 + lane] = sb[nt];
      }
    }
  }
  __syncthreads();
  #pragma unroll
  for (int mti = 0; mti < 2; ++mti)
    #pragma unroll
    for (int nt = 0; nt < 4; ++nt)
      #pragma unroll
      for (int r = 0; r < 4; ++r) {
        int row = w * 32 + mti * 16 + lhi * 4 + r;
        h2p[row * 64 + SWZ(row, nt * 16 + l15)] = acc[mti][nt][r];
      }
  __syncthreads();

  // ---- B2 producers ----
  float mu2, inv2;
  {
    float a = ps1[lane] + ps1[64 + lane] + ps1[128 + lane] + ps1[192 + lane];
    float b = ps2[lane] + ps2[64 + lane] + ps2[128 + lane] + ps2[192 + lane];
    mu2 = a * (1.0f / 128.0f);
    inv2 = 1.0f / sqrtf(b * (1.0f / 128.0f) - mu2 * mu2 + 1e-5f);
  }
  float hv[32];
  #pragma unroll
  for (int mi = 0; mi < 32; ++mi) {
    int row = w * 32 + mi;
    hv[mi] = h2p[row * 64 + SWZ(row, lane)];
  }
  __syncthreads();
  #pragma unroll
  for (int q = 0; q < 4; ++q) {
    float hbuf[8];
    #pragma unroll
    for (int j = 0; j < 8; ++j) {
      int mi = q * 8 + j, mm = w * 32 + mi;
      float gi = g2[mm] * inv2;
      float bb = fmaf(-mu2, gi, be2[mm]);
      hbuf[j] = fmaxf(fmaf(hv[mi], gi, bb), 0.f);
    }
    u32x4 vh, vl;
    #pragma unroll
    for (int e = 0; e < 4; ++e) {
      u2 s = split2(hbuf[2 * e], hbuf[2 * e + 1]);
      vh[e] = s.hi; vl[e] = s.lo;
    }
    int slotd = ((w * 4 + lhi) * 64 + q * 16 + l15) * 4;
    *(u32x4*)((unsigned*)B2hi + slotd) = vh;
    *(u32x4*)((unsigned*)B2lo + slotd) = vl;
  }
  __syncthreads();

  // ---- GEMM2: h3[64][64] = W3 @ h2 ----
  f32x4 acc2[4];
  #pragma unroll
  for (int b = 0; b < 4; ++b) acc2[b] = zero4;
  for (int kt = 0; kt < 4; ++kt) {
    bf16x8 ah = *(const bf16x8*)(W3Ah + ((w * 4 + kt) * 64 + lane) * 8);
    bf16x8 al = *(const bf16x8*)(W3Al + ((w * 4 + kt) * 64 + lane) * 8);
    #pragma unroll
    for (int nt = 0; nt < 4; ++nt) {
      bf16x8 bh = *(const bf16x8*)(B2hi + ((kt * 4 + nt) * 64 + lane) * 8);
      bf16x8 bl = *(const bf16x8*)(B2lo + ((kt * 4 + nt) * 64 + lane) * 8);
      acc2[nt] = MFMA(ah, bh, acc2[nt]);
      acc2[nt] = MFMA(ah, bl, acc2[nt]);
      acc2[nt] = MFMA(al, bh, acc2[nt]);
    }
  }
  {
    f32x4 bv = *(const f32x4*)(b3 + w * 16 + lhi * 4);
    #pragma unroll
    for (int nt = 0; nt < 4; ++nt) acc2[nt] += bv;
  }
  {
    float sa[4], sb[4];
    #pragma unroll
    for (int nt = 0; nt < 4; ++nt) {
      float x1 = 0.f, x2 = 0.f;
      #pragma unroll
      for (int r = 0; r < 4; ++r) { float v = acc2[nt][r]; x1 += v; x2 += v * v; }
      x1 += __shfl_xor(x1, 16, 64); x1 += __shfl_xor(x1, 32, 64);
      x2 += __shfl_xor(x2, 16, 64); x2 += __shfl_xor(x2, 32, 64);
      sa[nt] = x1; sb[nt] = x2;
    }
    if (lane < 16) {
      #pragma unroll
      for (int nt = 0; nt < 4; ++nt) {
        ps1[w * 64 + nt * 16 + lane] = sa[nt];
        ps2[w * 64 + nt * 16 + lane] = sb[nt];
      }
    }
  }
  __syncthreads();
  #pragma unroll
  for (int nt = 0; nt < 4; ++nt)
    #pragma unroll
    for (int r = 0; r < 4; ++r) {
      int row = w * 16 + lhi * 4 + r;
      h3p[row * 64 + SWZ(row, nt * 16 + l15)] = acc2[nt][r];
    }
  __syncthreads();

  // ---- B3 producers ----
  float mu3, inv3;
  {
    float a = ps1[lane] + ps1[64 + lane] + ps1[128 + lane] + ps1[192 + lane];
    float b = ps2[lane] + ps2[64 + lane] + ps2[128 + lane] + ps2[192 + lane];
    mu3 = a * (1.0f / 64.0f);
    inv3 = 1.0f / sqrtf(b * (1.0f / 64.0f) - mu3 * mu3 + 1e-5f);
  }
  #pragma unroll
  for (int q = 0; q < 2; ++q) {
    int o = w * 2 + q;        // octet 0..7
    float hbuf[8];
    #pragma unroll
    for (int j = 0; j < 8; ++j) {
      int mm = o * 8 + j;
      float v = h3p[mm * 64 + SWZ(mm, lane)];
      float gi = g3[mm] * inv3;
      float bb = fmaf(-mu3, gi, be3[mm]);
      hbuf[j] = fmaxf(fmaf(v, gi, bb), 0.f);
    }
    u32x4 vh, vl;
    #pragma unroll
    for (int e = 0; e < 4; ++e) {
      u2 s = split2(hbuf[2 * e], hbuf[2 * e + 1]);
      vh[e] = s.hi; vl[e] = s.lo;
    }
    int slotd = (((o >> 2) * 4 + lhi) * 64 + (o & 3) * 16 + l15) * 4;
    *(u32x4*)((unsigned*)B3hi + slotd) = vh;
    *(u32x4*)((unsigned*)B3lo + slotd) = vl;
  }
  __syncthreads();

  // ---- GEMM3: raw[64][64] = W4 @ h3 ----
  f32x4 acc3[4];
  #pragma unroll
  for (int b = 0; b < 4; ++b) acc3[b] = zero4;
  for (int kt = 0; kt < 2; ++kt) {
    bf16x8 ah = *(const bf16x8*)(W4Ah + ((w * 2 + kt) * 64 + lane) * 8);
    bf16x8 al = *(const bf16x8*)(W4Al + ((w * 2 + kt) * 64 + lane) * 8);
    #pragma unroll
    for (int nt = 0; nt < 4; ++nt) {
      bf16x8 bh = *(const bf16x8*)(B3hi + ((kt * 4 + nt) * 64 + lane) * 8);
      bf16x8 bl = *(const bf16x8*)(B3lo + ((kt * 4 + nt) * 64 + lane) * 8);
      acc3[nt] = MFMA(ah, bh, acc3[nt]);
      acc3[nt] = MFMA(ah, bl, acc3[nt]);
      acc3[nt] = MFMA(al, bh, acc3[nt]);
    }
  }
  f32x4 b4v = *(const f32x4*)(b4 + w * 16 + lhi * 4);
  unsigned long long kbest[4];
  #pragma unroll
  for (int nt = 0; nt < 4; ++nt) {
    unsigned long long am = adj[nt * 16 + l15];
    unsigned long long kb = 0ull;
    #pragma unroll
    for (int r = 0; r < 4; ++r) {
      int o = w * 16 + lhi * 4 + r;
      float raw = acc3[nt][r] + b4v[r];
      float val = ((am >> o) & 1ull) ? raw : -__builtin_huge_valf();
      unsigned u = __float_as_uint(val);
      u = (u & 0x80000000u) ? ~u : (u | 0x80000000u);
      unsigned long long key = ((unsigned long long)u << 6) | (unsigned long long)(63 - o);
      if (key > kb) kb = key;
    }
    unsigned long long oth = __shfl_xor(kb, 16, 64); if (oth > kb) kb = oth;
    oth = __shfl_xor(kb, 32, 64); if (oth > kb) kb = oth;
    kbest[nt] = kb;
  }
  if (lane < 16) {
    #pragma unroll
    for (int nt = 0; nt < 4; ++nt) pk[w * 64 + nt * 16 + lane] = kbest[nt];
  }
  __syncthreads();
  if (tid < 64) {
    unsigned long long k0 = pk[tid], k1 = pk[64 + tid];
    unsigned long long k2 = pk[128 + tid], k3 = pk[192 + tid];
    unsigned long long a = k0 > k1 ? k0 : k1;
    unsigned long long b = k2 > k3 ? k2 : k3;
    unsigned long long bb = a > b ? a : b;
    nxt[(size_t)i * 64 + tid] = (unsigned char)(63u - (unsigned)(bb & 63ull));
  }
}

// ---------------- trajectory via parallel map-composition scan ----------------

__global__ void k_scan_a(const unsigned char* __restrict__ nxt,
                         unsigned char* __restrict__ cmap) {
  int c = blockIdx.x, lane = threadIdx.x;
  int g = lane;
  const unsigned char* p = nxt + (size_t)c * 128 * 64;
  for (int s = 0; s < 128; ++s) {
    int sig = p[s * 64 + lane];
    g = __shfl(sig, g, 64);
  }
  cmap[c * 64 + lane] = (unsigned char)g;
}

__global__ void k_scan_b(const unsigned char* __restrict__ cmap,
                         int* __restrict__ startz) {
  int lane = threadIdx.x;
  int cur = 0;
  for (int c = 0; c < 256; ++c) {
    if (lane == 0) startz[c] = cur;
    int row = cmap[c * 64 + lane];
    cur = __shfl(row, cur, 64);
  }
}

__global__ void k_scan_c(const unsigned char* __restrict__ nxt,
                         const int* __restrict__ startz,
                         unsigned char* __restrict__ zones) {
  int c = blockIdx.x, lane = threadIdx.x;
  int cur = startz[c];
  const unsigned char* p = nxt + (size_t)c * 128 * 64;
  for (int s = 0; s < 128; ++s) {
    if (lane == 0) zones[c * 128 + s] = (unsigned char)cur;
    int row = p[s * 64 + lane];
    cur = __shfl(row, cur, 64);
  }
}

// ---------------- pass 2m: logits for actual zones, 64 timesteps/block, MFMA ----------------

__global__ __launch_bounds__(256, 2) void k_pass2m(
    const float* __restrict__ times, const unsigned char* __restrict__ zones,
    const float* __restrict__ c_pa, const float* __restrict__ w_t,
    const float* __restrict__ c_g, const float* __restrict__ c_const,
    const float* __restrict__ wzZ, const float* __restrict__ st,
    const unsigned short* __restrict__ W2Ah, const unsigned short* __restrict__ W2Al,
    const unsigned short* __restrict__ W3Ah, const unsigned short* __restrict__ W3Al,
    const unsigned short* __restrict__ W4Ah, const unsigned short* __restrict__ W4Al,
    const float* __restrict__ b2, const float* __restrict__ b3,
    const float* __restrict__ b4,
    const float* __restrict__ g1, const float* __restrict__ be1,
    const float* __restrict__ g2, const float* __restrict__ be2,
    const float* __restrict__ g3, const float* __restrict__ be3,
    const unsigned long long* __restrict__ adj,
    float* __restrict__ out) {
  __shared__ __align__(16) char region[32768];
  __shared__ float ps1[256], ps2[256];
  __shared__ unsigned long long am_lds[64];

  unsigned short* B1hi = (unsigned short*)region;
  unsigned short* B1lo = (unsigned short*)(region + 16384);
  float* h2p = (float*)region;
  unsigned short* B2hi = (unsigned short*)region;
  unsigned short* B2lo = (unsigned short*)(region + 16384);
  float* h3p = (float*)region;
  unsigned short* B3hi = (unsigned short*)(region + 16384);
  unsigned short* B3lo = (unsigned short*)(region + 24576);
  float* outT = (float*)region;                        // [64 b][64 o] swizzled

  const int tid = threadIdx.x;
  const int lane = tid & 63;          // lane == timestep b for producer phases
  const int l15 = lane & 15;
  const int lhi = lane >> 4;
  const int w = __builtin_amdgcn_readfirstlane(tid >> 6);
  const int i0 = blockIdx.x * 64;

  // per-lane timestep state
  const float t = times[i0 + lane];
  const int z = zones[i0 + lane];
  const int zrow = z << 8;
  if (tid < 64) am_lds[tid] = adj[zones[i0 + tid]];

  const float m0 = (st[384] + t + 1.0f) * (1.0f / 97.0f);
  const float e2 = (st[385] + t * t + 1.0f) * (1.0f / 97.0f);
  const float a0 = 1.0f / sqrtf(e2 - m0 * m0 + 1e-5f);   // alpha
  const float a1 = a0 * t;
  const float a2 = -m0 * a0;                              // gma

  // closed-form LN1 stats via Gram matrix
  float mu1, inv1;
  {
    float SP = st[386], SW = st[387], SG = st[388], SC = st[389];
    float PP = st[390], PW = st[391], PG = st[392], PC = st[393];
    float WW = st[394], WG = st[395], WC = st[396];
    float GG = st[397], GC = st[398], CC = st[399];
    float U1 = a0 * SP + a1 * SW + a2 * SG + SC;
    float s1 = fmaf(a0, st[z], U1);
    float Qu = a0 * a0 * PP + a1 * a1 * WW + a2 * a2 * GG + CC
             + 2.0f * (a0 * a1 * PW + a0 * a2 * PG + a0 * PC
                       + a1 * a2 * WG + a1 * WC + a2 * GC);
    float uwz = a0 * st[128 + z] + a1 * st[192 + z] + a2 * st[256 + z] + st[320 + z];
    float s2 = Qu + 2.0f * a0 * uwz + a0 * a0 * st[64 + z];
    mu1 = s1 * (1.0f / 256.0f);
    inv1 = 1.0f / sqrtf(s2 * (1.0f / 256.0f) - mu1 * mu1 + 1e-5f);
  }

  const f32x4 zero4 = {0.f, 0.f, 0.f, 0.f};
  f32x4 acc[2][4];
  #pragma unroll
  for (int a = 0; a < 2; ++a)
    #pragma unroll
    for (int b = 0; b < 4; ++b) acc[a][b] = zero4;

  for (int kc = 0; kc < 2; ++kc) {
    if (kc) __syncthreads();
    #pragma unroll
    for (int q = 0; q < 4; ++q) {
      int kb = kc * 128 + w * 32 + q * 8;
      float hbuf[8];
      #pragma unroll
      for (int j = 0; j < 8; ++j) {
        int k = kb + j;
        float u = fmaf(a0, c_pa[k], fmaf(a1, w_t[k], fmaf(a2, c_g[k], c_const[k])));
        float p = fmaf(a0, wzZ[zrow + k], u);
        float gi = g1[k] * inv1;
        float bb = fmaf(-mu1, gi, be1[k]);
        hbuf[j] = fmaxf(fmaf(p, gi, bb), 0.f);
      }
      u32x4 vh, vl;
      #pragma unroll
      for (int e = 0; e < 4; ++e) {
        u2 s = split2(hbuf[2 * e], hbuf[2 * e + 1]);
        vh[e] = s.hi; vl[e] = s.lo;
      }
      int slotd = ((w * 4 + lhi) * 64 + q * 16 + l15) * 4;
      *(u32x4*)((unsigned*)B1hi + slotd) = vh;
      *(u32x4*)((unsigned*)B1lo + slotd) = vl;
    }
    __syncthreads();
    for (int kt = 0; kt < 4; ++kt) {
      int ktg = kc * 4 + kt;
      bf16x8 a0h = *(const bf16x8*)(W2Ah + (((2 * w + 0) * 8 + ktg) * 64 + lane) * 8);
      bf16x8 a0l = *(const bf16x8*)(W2Al + (((2 * w + 0) * 8 + ktg) * 64 + lane) * 8);
      bf16x8 a1h = *(const bf16x8*)(W2Ah + (((2 * w + 1) * 8 + ktg) * 64 + lane) * 8);
      bf16x8 a1l = *(const bf16x8*)(W2Al + (((2 * w + 1) * 8 + ktg) * 64 + lane) * 8);
      #pragma unroll
      for (int nt = 0; nt < 4; ++nt) {
        bf16x8 bh = *(const bf16x8*)(B1hi + ((kt * 4 + nt) * 64 + lane) * 8);
        bf16x8 bl = *(const bf16x8*)(B1lo + ((kt * 4 + nt) * 64 + lane) * 8);
        acc[0][nt] = MFMA(a0h, bh, acc[0][nt]);
        acc[0][nt] = MFMA(a0h, bl, acc[0][nt]);
        acc[0][nt] = MFMA(a0l, bh, acc[0][nt]);
        acc[1][nt] = MFMA(a1h, bh, acc[1][nt]);
        acc[1][nt] = MFMA(a1h, bl, acc[1][nt]);
        acc[1][nt] = MFMA(a1l, bh, acc[1][nt]);
      }
    }
  }
  #pragma unroll
  for (int mti = 0; mti < 2; ++mti) {
    f32x4 bv = *(const f32x4*)(b2 + w * 32 + mti * 16 + lhi * 4);
    #pragma unroll
    for (int nt = 0; nt < 4; ++nt) acc[mti][nt] += bv;
  }
  {
    float sa[4], sb[4];
    #pragma unroll
    for (int nt = 0; nt < 4; ++nt) {
      float x1 = 0.f, x2 = 0.f;
      #pragma unroll
      for (int mti = 0; mti < 2; ++mti)
        #pragma unroll
        for (int r = 0; r < 4; ++r) { float v = acc[mti][nt][r]; x1 += v; x2 += v * v; }
      x1 += __shfl_xor(x1, 16, 64); x1 += __shfl_xor(x1, 32, 64);
      x2 += __shfl_xor(x2, 16, 64); x2 += __shfl_xor(x2, 32, 64);
      sa[nt] = x1; sb[nt] = x2;
    }
    if (lane < 16) {
      #pragma unroll
      for (int nt = 0; nt < 4; ++nt) {
        ps1[w * 64 + nt * 16 + lane] = sa[nt];
        ps2[w * 64 + nt * 16 + lane] = sb[nt];
      }
    }
  }
  __syncthreads();
  #pragma unroll
  for (int mti = 0; mti < 2; ++mti)
    #pragma unroll
    for (int nt = 0; nt < 4; ++nt)
      #pragma unroll
      for (int r = 0; r < 4; ++r) {
        int row = w * 32 + mti * 16 + lhi * 4 + r;
        h2p[row * 64 + SWZ(row, nt * 16 + l15)] = acc[mti][nt][r];
      }
  __syncthreads();

  float mu2, inv2;
  {
    float a = ps1[lane] + ps1[64 + lane] + ps1[128 + lane] + ps1[192 + lane];
    float b = ps2[lane] + ps2[64 + lane] + ps2[128 + lane] + ps2[192 + lane];
    mu2 = a * (1.0f / 128.0f);
    inv2 = 1.0f / sqrtf(b * (1.0f / 128.0f) - mu2 * mu2 + 1e-5f);
  }
  float hv[32];
  #pragma unroll
  for (int mi = 0; mi < 32; ++mi) {
    int row = w * 32 + mi;
    hv[mi] = h2p[row * 64 + SWZ(row, lane)];
  }
  __syncthreads();
  #pragma unroll
  for (int q = 0; q < 4; ++q) {
    float hbuf[8];
    #pragma unroll
    for (int j = 0; j < 8; ++j) {
      int mi = q * 8 + j, mm = w * 32 + mi;
      float gi = g2[mm] * inv2;
      float bb = fmaf(-mu2, gi, be2[mm]);
      hbuf[j] = fmaxf(fmaf(hv[mi], gi, bb), 0.f);
    }
    u32x4 vh, vl;
    #pragma unroll
    for (int e = 0; e < 4; ++e) {
      u2 s = split2(hbuf[2 * e], hbuf[2 * e + 1]);
      vh[e] = s.hi; vl[e] = s.lo;
    }
    int slotd = ((w * 4 + lhi) * 64 + q * 16 + l15) * 4;
    *(u32x4*)((unsigned*)B2hi + slotd) = vh;
    *(u32x4*)((unsigned*)B2lo + slotd) = vl;
  }
  __syncthreads();

  f32x4 acc2[4];
  #pragma unroll
  for (int b = 0; b < 4; ++b) acc2[b] = zero4;
  for (int kt = 0; kt < 4; ++kt) {
    bf16x8 ah = *(const bf16x8*)(W3Ah + ((w * 4 + kt) * 64 + lane) * 8);
    bf16x8 al = *(const bf16x8*)(W3Al + ((w * 4 + kt) * 64 + lane) * 8);
    #pragma unroll
    for (int nt = 0; nt < 4; ++nt) {
      bf16x8 bh = *(const bf16x8*)(B2hi + ((kt * 4 + nt) * 64 + lane) * 8);
      bf16x8 bl = *(const bf16x8*)(B2lo + ((kt * 4 + nt) * 64 + lane) * 8);
      acc2[nt] = MFMA(ah, bh, acc2[nt]);
      acc2[nt] = MFMA(ah, bl, acc2[nt]);
      acc2[nt] = MFMA(al, bh, acc2[nt]);
    }
  }
  {
    f32x4 bv = *(const f32x4*)(b3 + w * 16 + lhi * 4);
    #pragma unroll
    for (int nt = 0; nt < 4; ++nt) acc2[nt] += bv;
  }
  {
    float sa[4], sb[4];
    #pragma unroll
    for (int nt = 0; nt < 4; ++nt) {
      float x1 = 0.f, x2 = 0.f;
      #pragma unroll
      for (int r = 0; r < 4; ++r) { float v = acc2[nt][r]; x1 += v; x2 += v * v; }
      x1 += __shfl_xor(x1, 16, 64); x1 += __shfl_xor(x1, 32, 64);
      x2 += __shfl_xor(x2, 16, 64); x2 += __shfl_xor(x2, 32, 64);
      sa[nt] = x1; sb[nt] = x2;
    }
    if (lane < 16) {
      #pragma unroll
      for (int nt = 0; nt < 4; ++nt) {
        ps1[w * 64 + nt * 16 + lane] = sa[nt];
        ps2[w * 64 + nt * 16 + lane] = sb[nt];
      }
    }
  }
  __syncthreads();
  #pragma unroll
  for (int nt = 0; nt < 4; ++nt)
    #pragma unroll
    for (int r = 0; r < 4; ++r) {
      int row = w * 16 + lhi * 4 + r;
      h3p[row * 64 + SWZ(row, nt * 16 + l15)] = acc2[nt][r];
    }
  __syncthreads();

  float mu3, inv3;
  {
    float a = ps1[lane] + ps1[64 + lane] + ps1[128 + lane] + ps1[192 + lane];
    float b = ps2[lane] + ps2[64 + lane] + ps2[128 + lane] + ps2[192 + lane];
    mu3 = a * (1.0f / 64.0f);
    inv3 = 1.0f / sqrtf(b * (1.0f / 64.0f) - mu3 * mu3 + 1e-5f);
  }
  #pragma unroll
  for (int q = 0; q < 2; ++q) {
    int o = w * 2 + q;
    float hbuf[8];
    #pragma unroll
    for (int j = 0; j < 8; ++j) {
      int mm = o * 8 + j;
      float v = h3p[mm * 64 + SWZ(mm, lane)];
      float gi = g3[mm] * inv3;
      float bb = fmaf(-mu3, gi, be3[mm]);
      hbuf[j] = fmaxf(fmaf(v, gi, bb), 0.f);
    }
    u32x4 vh, vl;
    #pragma unroll
    for (int e = 0; e < 4; ++e) {
      u2 s = split2(hbuf[2 * e], hbuf[2 * e + 1]);
      vh[e] = s.hi; vl[e] = s.lo;
    }
    int slotd = (((o >> 2) * 4 + lhi) * 64 + (o & 3) * 16 + l15) * 4;
    *(u32x4*)((unsigned*)B3hi + slotd) = vh;
    *(u32x4*)((unsigned*)B3lo + slotd) = vl;
  }
  __syncthreads();

  f32x4 acc3[4];
  #pragma unroll
  for (int b = 0; b < 4; ++b) acc3[b] = zero4;
  for (int kt = 0; kt < 2; ++kt) {
    bf16x8 ah = *(const bf16x8*)(W4Ah + ((w * 2 + kt) * 64 + lane) * 8);
    bf16x8 al = *(const bf16x8*)(W4Al + ((w * 2 + kt) * 64 + lane) * 8);
    #pragma unroll
    for (int nt = 0; nt < 4; ++nt) {
      bf16x8 bh = *(const bf16x8*)(B3hi + ((kt * 4 + nt) * 64 + lane) * 8);
      bf16x8 bl = *(const bf16x8*)(B3lo + ((kt * 4 + nt) * 64 + lane) * 8);
      acc3[nt] = MFMA(ah, bh, acc3[nt]);
      acc3[nt] = MFMA(ah, bl, acc3[nt]);
      acc3[nt] = MFMA(al, bh, acc3[nt]);
    }
  }
  // epilogue: +b4, mask by actual-zone adjacency, transpose via LDS, store
  f32x4 b4v = *(const f32x4*)(b4 + w * 16 + lhi * 4);
  #pragma unroll
  for (int nt = 0; nt < 4; ++nt) {
    unsigned long long am = am_lds[nt * 16 + l15];
    #pragma unroll
    for (int r = 0; r < 4; ++r) {
      int o = w * 16 + lhi * 4 + r;
      float raw = acc3[nt][r] + b4v[r];
      float predv = ((am >> o) & 1ull) ? raw : -50.0f;
      int b = nt * 16 + l15;
      outT[b * 64 + SWZ(b, o)] = predv;
    }
  }
  __syncthreads();
  {
    int b = tid >> 2, cb = (tid & 3) * 16;
    size_t gbase = ((size_t)(i0 + b)) * 64 + cb;
    #pragma unroll
    for (int c4 = 0; c4 < 4; ++c4) {
      int col = cb + c4 * 4;
      f32x4 v = *(const f32x4*)(outT + b * 64 + SWZ(b, col));
      *(f32x4*)(out + gbase + c4 * 4) = v;
    }
  }
}

// ---------------- launch ----------------

extern "C" void kernel_launch(void* const* d_in, const int* in_sizes, int n_in,
                              void* d_out, int out_size, void* d_ws, size_t ws_size,
                              hipStream_t stream) {
  const float* pa    = (const float*)d_in[0];
  const float* times = (const float*)d_in[1];
  const int*   ei    = (const int*)d_in[3];
  const float* g0    = (const float*)d_in[4];
  const float* b0    = (const float*)d_in[5];
  const float* W1    = (const float*)d_in[6];
  const float* b1    = (const float*)d_in[7];
  const float* g1    = (const float*)d_in[8];
  const float* be1   = (const float*)d_in[9];
  const float* W2    = (const float*)d_in[10];
  const float* b2    = (const float*)d_in[11];
  const float* g2    = (const float*)d_in[12];
  const float* be2   = (const float*)d_in[13];
  const float* W3    = (const float*)d_in[14];
  const float* b3    = (const float*)d_in[15];
  const float* g3    = (const float*)d_in[16];
  const float* be3   = (const float*)d_in[17];
  const float* W4    = (const float*)d_in[18];
  const float* b4    = (const float*)d_in[19];

  char* ws = (char*)d_ws;
  float* c_pa    = (float*)(ws + 0);
  float* w_t     = (float*)(ws + 1024);
  float* c_g     = (float*)(ws + 2048);
  float* c_const = (float*)(ws + 3072);
  float* scal    = (float*)(ws + 4096);
  unsigned long long* adj = (unsigned long long*)(ws + 4608);
  float* wzT = (float*)(ws + 5120);                       // 64 KB
  float* wzZ = (float*)(ws + 70656);                      // 64 KB
  unsigned short* W2Ah = (unsigned short*)(ws + 136192);  // 64 KB
  unsigned short* W2Al = (unsigned short*)(ws + 201728);  // 64 KB
  unsigned short* W3Ah = (unsigned short*)(ws + 267264);  // 16 KB
  unsigned short* W3Al = (unsigned short*)(ws + 283648);  // 16 KB
  unsigned short* W4Ah = (unsigned short*)(ws + 300032);  // 8 KB
  unsigned short* W4Al = (unsigned short*)(ws + 308224);  // 8 KB
  float* st = (float*)(ws + 316416);                      // 400 floats
  unsigned char* nxt  = (unsigned char*)(ws + 318464);    // 2 MB
  unsigned char* cmap = (unsigned char*)(ws + 2415616);   // 16 KB
  int* startz = (int*)(ws + 2432000);                     // 1 KB
  unsigned char* zones = (unsigned char*)(ws + 2433024);  // 32 KB

  k_prep<<<1, 256, 0, stream>>>(pa, g0, b0, W1, b1, c_pa, w_t, c_g, c_const,
                                scal, wzT, wzZ);
  k_prep2<<<1, 128, 0, stream>>>(c_pa, w_t, c_g, c_const, wzT, st);
  k_scal2st<<<1, 64, 0, stream>>>(scal, st);
  k_adj<<<1, 256, 0, stream>>>(ei, adj);
  k_wsplit<<<176, 256, 0, stream>>>(W2, W3, W4, W2Ah, W2Al, W3Ah, W3Al, W4Ah, W4Al);
  k_pass1<<<32768, 256, 0, stream>>>(times, c_pa, w_t, c_g, c_const, wzT, st,
                                     W2Ah, W2Al, W3Ah, W3Al, W4Ah, W4Al,
                                     b2, b3, b4, g1, be1, g2, be2, g3, be3,
                                     adj, nxt);
  k_scan_a<<<256, 64, 0, stream>>>(nxt, cmap);
  k_scan_b<<<1, 64, 0, stream>>>(cmap, startz);
  k_scan_c<<<256, 64, 0, stream>>>(nxt, startz, zones);
  k_pass2m<<<512, 256, 0, stream>>>(times, zones, c_pa, w_t, c_g, c_const,
                                    wzZ, st, W2Ah, W2Al, W3Ah, W3Al, W4Ah, W4Al,
                                    b2, b3, b4, g1, be1, g2, be2, g3, be3,
                                    adj, (float*)d_out);
}